// Round 4
// baseline (540.114 us; speedup 1.0000x reference)
//
#include <hip/hip_runtime.h>
#include <hip/hip_bf16.h>

#define BB 2
#define SS 4096
#define DD 1024
#define HH 16
#define WW 256
#define FF 4096
#define HDIM 64
#define NBLK (SS / WW)       /* 16 */
#define MROWS (BB * SS)      /* 8192 */

typedef short bfrag8 __attribute__((ext_vector_type(8)));
typedef float floatx4 __attribute__((ext_vector_type(4)));

__device__ __forceinline__ float bf2f(ushort u) {
    union { uint i; float f; } c; c.i = ((uint)u) << 16; return c.f;
}
__device__ __forceinline__ ushort f2bf(float f) {
    union { float f; uint i; } c; c.f = f;
    uint r = (c.i + 0x7FFFu + ((c.i >> 16) & 1u)) >> 16;
    return (ushort)r;
}
// gelu(tanh approx) == x * sigmoid(2z), z = 0.79788456(x + 0.044715 x^3)
__device__ __forceinline__ float gelu_fast(float x) {
    float z2 = 1.5957691216057308f * x * (1.f + 0.044715f * x * x); // 2z
    return x / (1.f + __expf(-z2));
}

// async global->LDS, 16B per lane. LDS dest must be contiguous in lane order.
__device__ __forceinline__ void gload_lds16(const ushort* g, ushort* l) {
    __builtin_amdgcn_global_load_lds(
        (const __attribute__((address_space(1))) void*)g,
        (__attribute__((address_space(3))) void*)l, 16, 0, 0);
}

// ---------------------------------------------------------------------------
// f32 -> bf16 bulk convert (grid * 1024 elements)
// ---------------------------------------------------------------------------
__global__ __launch_bounds__(256) void cvt_f32_bf16(
    const float* __restrict__ in, ushort* __restrict__ out)
{
    size_t i = ((size_t)blockIdx.x * 256 + threadIdx.x) * 4;
    float4 v = *(const float4*)(in + i);
    union { ushort u[4]; uint2 d; } t;
    t.u[0] = f2bf(v.x); t.u[1] = f2bf(v.y);
    t.u[2] = f2bf(v.z); t.u[3] = f2bf(v.w);
    *(uint2*)(out + i) = t.d;
}

// ---------------------------------------------------------------------------
// Fused transpose-convert of ALL weights: f32 [K][N] -> bf16 [N][K].
// grid = (128, 32, 6); z selects the weight. 32x32 LDS tiles.
// ---------------------------------------------------------------------------
__global__ __launch_bounds__(256) void cvt_transpose_all(
    const float* __restrict__ Wq, const float* __restrict__ Wk,
    const float* __restrict__ Wv, const float* __restrict__ Wo,
    const float* __restrict__ W1, const float* __restrict__ W2,
    ushort* __restrict__ WqkvT, ushort* __restrict__ WoT,
    ushort* __restrict__ W1t, ushort* __restrict__ W2t)
{
    __shared__ ushort sT[32][33];
    const int z = blockIdx.z;
    const float* in; ushort* out; int K, N, n0, k0;
    if (z < 4) {
        if (blockIdx.x >= 32) return;
        in  = (z == 0) ? Wq : (z == 1) ? Wk : (z == 2) ? Wv : Wo;
        out = (z < 3) ? WqkvT + (size_t)z * 1024 * 1024 : WoT;
        K = 1024; N = 1024;
        n0 = blockIdx.x * 32; k0 = blockIdx.y * 32;
    } else if (z == 4) {
        in = W1; out = W1t; K = 1024; N = 4096;
        n0 = blockIdx.x * 32; k0 = blockIdx.y * 32;
    } else {
        in = W2; out = W2t; K = 4096; N = 1024;
        n0 = blockIdx.y * 32; k0 = blockIdx.x * 32;
    }

    const int r  = threadIdx.x >> 3;        // 0..31
    const int c4 = (threadIdx.x & 7) * 4;   // 0..28

    float4 v = *(const float4*)(in + (size_t)(k0 + r) * N + n0 + c4);
    sT[c4 + 0][r] = f2bf(v.x);
    sT[c4 + 1][r] = f2bf(v.y);
    sT[c4 + 2][r] = f2bf(v.z);
    sT[c4 + 3][r] = f2bf(v.w);
    __syncthreads();
    union { ushort u[4]; uint2 d; } t;
#pragma unroll
    for (int e = 0; e < 4; ++e) t.u[e] = sT[r][c4 + e];
    *(uint2*)(out + (size_t)(n0 + r) * K + k0 + c4) = t.d;
}

// ---------------------------------------------------------------------------
// GEMM core: 128x256 tile, 512 threads = 8 waves (2M x 4N), per-wave 64x64.
// BK=64. TRIPLE-buffered LDS ring (144 KB) -> ONE s_barrier + counted
// vmcnt(6) per K-tile, 32 MFMAs between barriers. buf[t%3] is re-staged at
// iteration t+1, so the entry waitcnt carries lgkmcnt(0): every wave's LDS
// reads provably complete before it arrives at the barrier (prevents the
// rule-#18 MFMA-sink race). vmcnt(6) leaves tile t+1's 6 loads in flight
// across the barrier. Swizzle formulas identical to the verified 128x128
// kernel (0 bank conflicts).
// ---------------------------------------------------------------------------
__device__ __forceinline__ void gemm_core_128x256(
    const ushort* __restrict__ A, const ushort* __restrict__ Bt,
    int K, int m0, int n0, floatx4 (&acc)[4][4])
{
    __shared__ __align__(16) ushort sA[3][128 * 64];
    __shared__ __align__(16) ushort sB[3][256 * 64];

    const int tid  = threadIdx.x;
    const int lane = tid & 63;
    const int wave = tid >> 6;
    const int wm   = (wave >> 2) * 64;
    const int wn   = (wave & 3) * 64;
    const int lrow = lane & 15;
    const int quad = lane >> 4;

#pragma unroll
    for (int i = 0; i < 4; ++i)
#pragma unroll
        for (int j = 0; j < 4; ++j)
            acc[i][j] = (floatx4){0.f, 0.f, 0.f, 0.f};

    // per-thread staging source pointers (XOR-swizzled source columns,
    // linear LDS dest; dest granule d holds source granule d ^ (row&7))
    const ushort* aptr[2];
    const ushort* bptr[4];
#pragma unroll
    for (int it = 0; it < 2; ++it) {
        int c = it * 512 + tid;
        int row = c >> 3;
        int scol = ((c ^ (row & 7)) & 7) << 3;
        aptr[it] = A + (size_t)(m0 + row) * K + scol;
    }
#pragma unroll
    for (int it = 0; it < 4; ++it) {
        int c = it * 512 + tid;
        int row = c >> 3;
        int scol = ((c ^ (row & 7)) & 7) << 3;
        bptr[it] = Bt + (size_t)(n0 + row) * K + scol;
    }

    auto stage = [&](int buf, int kofs) {
#pragma unroll
        for (int it = 0; it < 2; ++it)
            gload_lds16(aptr[it] + kofs, (ushort*)&sA[buf][(it * 512 + tid) * 8]);
#pragma unroll
        for (int it = 0; it < 4; ++it)
            gload_lds16(bptr[it] + kofs, (ushort*)&sB[buf][(it * 512 + tid) * 8]);
    };

    const int NT = K >> 6;

    // prologue: tiles 0 and 1 in flight (12 outstanding loads)
    stage(0, 0);
    stage(1, 64);

    for (int t = 0; t < NT; ++t) {
        const int cur = t % 3;

        // entry: drain tile t's 6 loads (t+1's stay in flight) AND all of
        // this wave's LDS reads; then barrier -> everyone's reads of the
        // buffer to be re-staged are done.
        if (t < NT - 1)
            asm volatile("s_waitcnt vmcnt(6) lgkmcnt(0)" ::: "memory");
        else
            asm volatile("s_waitcnt vmcnt(0) lgkmcnt(0)" ::: "memory");
        __builtin_amdgcn_s_barrier();
        __builtin_amdgcn_sched_barrier(0);

        // stage tile t+2 into buf[(t+2)%3] == buf[(t-1)%3] (readers done)
        if (t + 2 < NT) stage((t + 2) % 3, (t + 2) * 64);

        // fragment reads (compiler inserts fine-grained lgkmcnt)
        bfrag8 af[4][2], bf[4][2];
#pragma unroll
        for (int mt = 0; mt < 4; ++mt) {
            int row = wm + mt * 16 + lrow;
#pragma unroll
            for (int ks = 0; ks < 2; ++ks) {
                int G = ks * 4 + quad;
                af[mt][ks] = *(const bfrag8*)&sA[cur][row * 64 + (((G ^ row) & 7) << 3)];
            }
        }
#pragma unroll
        for (int nt = 0; nt < 4; ++nt) {
            int row = wn + nt * 16 + lrow;
#pragma unroll
            for (int ks = 0; ks < 2; ++ks) {
                int G = ks * 4 + quad;
                bf[nt][ks] = *(const bfrag8*)&sB[cur][row * 64 + (((G ^ row) & 7) << 3)];
            }
        }

        __builtin_amdgcn_s_setprio(1);
#pragma unroll
        for (int ks = 0; ks < 2; ++ks)
#pragma unroll
            for (int mt = 0; mt < 4; ++mt)
#pragma unroll
                for (int nt = 0; nt < 4; ++nt)
                    acc[mt][nt] = __builtin_amdgcn_mfma_f32_16x16x32_bf16(
                        bf[nt][ks], af[mt][ks], acc[mt][nt], 0, 0, 0);
        __builtin_amdgcn_s_setprio(0);
    }
}

// XCD-aware bijective tile mapping. BM=128, BN=256.
__device__ __forceinline__ void tile_map(int M, int N, int& m0, int& n0)
{
    const int ntn = N >> 8;
    const int ntm = M >> 7;
    const int xcd = blockIdx.x & 7;
    const int idx = blockIdx.x >> 3;
    int mi, ni;
    if ((ntn & 7) == 0) {              // n-band per XCD
        const int nb = ntn >> 3;
        ni = xcd * nb + idx % nb;
        mi = idx / nb;
    } else {                           // m-band per XCD (ntm % 8 == 0)
        ni = idx % ntn;
        mi = xcd * (ntm >> 3) + idx / ntn;
    }
    m0 = mi * 128; n0 = ni * 256;
}

__global__ __launch_bounds__(512, 1) void gemm_pl(
    const ushort* __restrict__ A, const ushort* __restrict__ Bt,
    const float* __restrict__ bias, ushort* __restrict__ C,
    int M, int N, int K, int act)
{
    int m0, n0;
    tile_map(M, N, m0, n0);

    floatx4 acc[4][4];
    gemm_core_128x256(A, Bt, K, m0, n0, acc);

    const int tid  = threadIdx.x;
    const int lane = tid & 63;
    const int wave = tid >> 6;
    const int wm   = (wave >> 2) * 64;
    const int wn   = (wave & 3) * 64;
    const int lrow = lane & 15;
    const int quad = lane >> 4;

    // epilogue: row = m0+wm+mt*16+lrow, col-chunk = n0+wn+nt*16+quad*4
#pragma unroll
    for (int nt = 0; nt < 4; ++nt) {
        int nb = n0 + wn + nt * 16 + quad * 4;
        union { float4 v; float f[4]; } b4;
        b4.v = *(const float4*)(bias + nb);
#pragma unroll
        for (int mt = 0; mt < 4; ++mt) {
            int row = m0 + wm + mt * 16 + lrow;
            union { ushort u[4]; uint2 d; } t;
#pragma unroll
            for (int r = 0; r < 4; ++r) {
                float v = acc[mt][nt][r] + b4.f[r];
                if (act) v = gelu_fast(v);
                t.u[r] = f2bf(v);
            }
            *(uint2*)(C + (size_t)row * N + nb) = t.d;
        }
    }
}

// ---------------------------------------------------------------------------
// Fused QKV GEMM (verified 2-phase 128x128): A[8192][1024] @ [Wq|Wk|Wv]
// (Bt = [3072][1024]), BK=64, swizzled staging, XCD-aware 1D grid
// (1536 blocks). cols [0,1024) -> qb; [1024,2048) -> kb;
// [2048,3072) -> vT [b][h][dh][s] (swapped-operand MFMA).
// ---------------------------------------------------------------------------
__global__ __launch_bounds__(256) void gemm_qkv(
    const ushort* __restrict__ A, const ushort* __restrict__ Bt,
    const float* __restrict__ bq, const float* __restrict__ bk,
    const float* __restrict__ bv,
    ushort* __restrict__ qb, ushort* __restrict__ kb, ushort* __restrict__ vT)
{
    __shared__ ushort sA[128 * 64];
    __shared__ ushort sB[128 * 64];
    const int K = DD;

    const int tid  = threadIdx.x;
    const int nx   = 24, nyg = 8;
    const int gid  = blockIdx.x;
    const int j    = gid >> 3;
    const int m0   = ((gid & 7) * nyg + j / nx) * 128;
    const int n0   = (j % nx) * 128;
    const int wave = tid >> 6;
    const int lane = tid & 63;
    const int wm   = (wave >> 1) * 64;
    const int wn   = (wave & 1) * 64;
    const int lrow = lane & 15;
    const int quad = lane >> 4;
    const int sel  = n0 >> 10;               // block-uniform: 0=q 1=k 2=v

    floatx4 acc[4][4];
#pragma unroll
    for (int i = 0; i < 4; ++i)
#pragma unroll
        for (int j2 = 0; j2 < 4; ++j2)
            acc[i][j2] = (floatx4){0.f, 0.f, 0.f, 0.f};

    for (int k0 = 0; k0 < K; k0 += 64) {
#pragma unroll
        for (int it = 0; it < 4; ++it) {
            int c    = it * 256 + tid;
            int row  = c >> 3;
            int scol = ((c ^ (row & 7)) & 7) << 3;
            gload_lds16(A  + (size_t)(m0 + row) * K + k0 + scol, &sA[c * 8]);
            gload_lds16(Bt + (size_t)(n0 + row) * K + k0 + scol, &sB[c * 8]);
        }
        __syncthreads();

#pragma unroll
        for (int ks = 0; ks < 2; ++ks) {
            bfrag8 af[4], bfv[4];
#pragma unroll
            for (int mt = 0; mt < 4; ++mt) {
                int row = wm + mt * 16 + lrow;
                int G   = ks * 4 + quad;
                af[mt] = *(const bfrag8*)&sA[row * 64 + (((G ^ row) & 7) << 3)];
            }
#pragma unroll
            for (int nt = 0; nt < 4; ++nt) {
                int row = wn + nt * 16 + lrow;
                int G   = ks * 4 + quad;
                bfv[nt] = *(const bfrag8*)&sB[row * 64 + (((G ^ row) & 7) << 3)];
            }
            if (sel < 2) {
#pragma unroll
                for (int mt = 0; mt < 4; ++mt)
#pragma unroll
                    for (int nt = 0; nt < 4; ++nt)
                        acc[mt][nt] = __builtin_amdgcn_mfma_f32_16x16x32_bf16(
                            bfv[nt], af[mt], acc[mt][nt], 0, 0, 0);
            } else {
#pragma unroll
                for (int mt = 0; mt < 4; ++mt)
#pragma unroll
                    for (int nt = 0; nt < 4; ++nt)
                        acc[mt][nt] = __builtin_amdgcn_mfma_f32_16x16x32_bf16(
                            af[mt], bfv[nt], acc[mt][nt], 0, 0, 0);
            }
        }
        __syncthreads();
    }

    if (sel < 2) {
        ushort* C = (sel == 0) ? qb : kb;
        const float* bias = (sel == 0) ? bq : bk;
        const int colbase = n0 + wn;
#pragma unroll
        for (int nt = 0; nt < 4; ++nt) {
            int nb = (colbase + nt * 16 + quad * 4) & 1023;
            union { float4 v; float f[4]; } b4;
            b4.v = *(const float4*)(bias + nb);
#pragma unroll
            for (int mt = 0; mt < 4; ++mt) {
                int row = m0 + wm + mt * 16 + lrow;
                union { ushort u[4]; uint2 d; } t;
#pragma unroll
                for (int r = 0; r < 4; ++r) t.u[r] = f2bf(acc[mt][nt][r] + b4.f[r]);
                *(uint2*)(C + (size_t)row * DD + nb) = t.d;
            }
        }
    } else {
        const int colbase = n0 + wn;
#pragma unroll
        for (int nt = 0; nt < 4; ++nt) {
            int cc = (colbase + nt * 16 + lrow) & 1023;
            int h = cc >> 6, dh = cc & 63;
            float bb = bv[cc];
#pragma unroll
            for (int mt = 0; mt < 4; ++mt) {
                int row0 = m0 + wm + mt * 16 + (quad << 2);
                int b = row0 >> 12, s = row0 & 4095;
                union { ushort u[4]; uint2 d; } t;
#pragma unroll
                for (int r = 0; r < 4; ++r) t.u[r] = f2bf(acc[mt][nt][r] + bb);
                *(uint2*)(vT + (size_t)(((b * HH + h) * HDIM + dh)) * SS + s) = t.d;
            }
        }
    }
}

// ---------------------------------------------------------------------------
// Barrier-free MFMA flash attention. One wave per block; block = (qt, h, b).
// S^T = K·Q^T -> online softmax -> P via swizzled LDS -> O^T += V^T·P^T
// (V^T straight from global vT). No __syncthreads.
// ---------------------------------------------------------------------------
__global__ __launch_bounds__(64, 2) void attn_flash(
    const ushort* __restrict__ q, const ushort* __restrict__ k,
    const ushort* __restrict__ vT, ushort* __restrict__ out)
{
    __shared__ ushort sP[64 * 72];

    const int qt = blockIdx.x, h = blockIdx.y, b = blockIdx.z;
    const int lane = threadIdx.x;
    const int c16  = lane & 15;
    const int quad = lane >> 4;
    const float CC = 0.18033688011112042f;   // (1/sqrt(64)) * log2(e)

    bfrag8 qf[4][2];
    {
        const size_t qbase = ((size_t)b * SS + qt * 64) * DD + h * HDIM;
#pragma unroll
        for (int nt = 0; nt < 4; ++nt)
#pragma unroll
            for (int ks = 0; ks < 2; ++ks)
                qf[nt][ks] = *(const bfrag8*)(q + qbase +
                    (size_t)(nt * 16 + c16) * DD + ks * 32 + quad * 8);
    }

    floatx4 oacc[4][4];
#pragma unroll
    for (int i = 0; i < 4; ++i)
#pragma unroll
        for (int j = 0; j < 4; ++j)
            oacc[i][j] = (floatx4){0.f, 0.f, 0.f, 0.f};
    float mrow[4], lsum[4];
#pragma unroll
    for (int i = 0; i < 4; ++i) { mrow[i] = -1e30f; lsum[i] = 0.f; }

    const int st0 = (qt - 4 > 0) ? qt - 4 : 0;
    const int st1 = (qt + 4 < 63) ? qt + 4 : 63;
    const size_t kb_b  = (size_t)b * SS * DD + h * HDIM;
    const size_t vT_b  = (size_t)((b * HH + h) * HDIM) * SS;

    for (int st = st0; st <= st1; ++st) {
        const int dlt = st - qt;

        floatx4 sacc[4][4];
#pragma unroll
        for (int i = 0; i < 4; ++i)
#pragma unroll
            for (int j = 0; j < 4; ++j)
                sacc[i][j] = (floatx4){0.f, 0.f, 0.f, 0.f};
#pragma unroll
        for (int ks = 0; ks < 2; ++ks) {
            bfrag8 kf[4];
#pragma unroll
            for (int mt = 0; mt < 4; ++mt)
                kf[mt] = *(const bfrag8*)(k + kb_b +
                    (size_t)(st * 64 + mt * 16 + c16) * DD + ks * 32 + quad * 8);
#pragma unroll
            for (int mt = 0; mt < 4; ++mt)
#pragma unroll
                for (int nt = 0; nt < 4; ++nt)
                    sacc[mt][nt] = __builtin_amdgcn_mfma_f32_16x16x32_bf16(
                        kf[mt], qf[nt][ks], sacc[mt][nt], 0, 0, 0);
        }

        if (dlt == 4 || dlt == -4) {
#pragma unroll
            for (int mt = 0; mt < 4; ++mt)
#pragma unroll
                for (int nt = 0; nt < 4; ++nt)
#pragma unroll
                    for (int r = 0; r < 4; ++r) {
                        int kl = mt * 16 + quad * 4 + r;
                        int ql = nt * 16 + c16;
                        bool ok = (dlt < 0) ? (kl >= ql) : (kl <= ql);
                        if (!ok) sacc[mt][nt][r] = -1e30f;
                    }
        }

        float pm[4];
#pragma unroll
        for (int nt = 0; nt < 4; ++nt) {
            float a0 = fmaxf(fmaxf(sacc[0][nt][0], sacc[0][nt][1]),
                             fmaxf(sacc[0][nt][2], sacc[0][nt][3]));
            float a1 = fmaxf(fmaxf(sacc[1][nt][0], sacc[1][nt][1]),
                             fmaxf(sacc[1][nt][2], sacc[1][nt][3]));
            float a2 = fmaxf(fmaxf(sacc[2][nt][0], sacc[2][nt][1]),
                             fmaxf(sacc[2][nt][2], sacc[2][nt][3]));
            float a3 = fmaxf(fmaxf(sacc[3][nt][0], sacc[3][nt][1]),
                             fmaxf(sacc[3][nt][2], sacc[3][nt][3]));
            pm[nt] = fmaxf(fmaxf(a0, a1), fmaxf(a2, a3));
            pm[nt] = fmaxf(pm[nt], __shfl_xor(pm[nt], 16, 64));
            pm[nt] = fmaxf(pm[nt], __shfl_xor(pm[nt], 32, 64));
        }
        float al[4];
#pragma unroll
        for (int nt = 0; nt < 4; ++nt) {
            float mn = fmaxf(mrow[nt], pm[nt]);
            al[nt] = exp2f((mrow[nt] - mn) * CC);
            mrow[nt] = mn;
        }
        float ps[4] = {0.f, 0.f, 0.f, 0.f};
#pragma unroll
        for (int mt = 0; mt < 4; ++mt)
#pragma unroll
            for (int nt = 0; nt < 4; ++nt)
#pragma unroll
                for (int r = 0; r < 4; ++r) {
                    float p = exp2f((sacc[mt][nt][r] - mrow[nt]) * CC);
                    sacc[mt][nt][r] = p;
                    ps[nt] += p;
                }
#pragma unroll
        for (int nt = 0; nt < 4; ++nt) {
            ps[nt] += __shfl_xor(ps[nt], 16, 64);
            ps[nt] += __shfl_xor(ps[nt], 32, 64);
            lsum[nt] = lsum[nt] * al[nt] + ps[nt];
        }

#pragma unroll
        for (int mt = 0; mt < 4; ++mt)
#pragma unroll
            for (int nt = 0; nt < 4; ++nt) {
                int row = nt * 16 + c16;
                int g   = (2 * mt + (quad >> 1)) ^ (row & 3);
                union { ushort u[4]; uint2 d; } t;
#pragma unroll
                for (int r = 0; r < 4; ++r) t.u[r] = f2bf(sacc[mt][nt][r]);
                *(uint2*)&sP[row * 72 + g * 8 + (quad & 1) * 4] = t.d;
            }

#pragma unroll
        for (int dt = 0; dt < 4; ++dt)
#pragma unroll
            for (int nq = 0; nq < 4; ++nq)
#pragma unroll
                for (int r = 0; r < 4; ++r)
                    oacc[dt][nq][r] *= al[nq];

#pragma unroll
        for (int ks = 0; ks < 2; ++ks) {
            bfrag8 vf[4], pf[4];
#pragma unroll
            for (int dt = 0; dt < 4; ++dt)
                vf[dt] = *(const bfrag8*)(vT + vT_b +
                    (size_t)(dt * 16 + c16) * SS + st * 64 + ks * 32 + quad * 8);
#pragma unroll
            for (int nq = 0; nq < 4; ++nq) {
                int row = nq * 16 + c16;
                int g   = (4 * ks + quad) ^ (row & 3);
                pf[nq] = *(const bfrag8*)&sP[row * 72 + g * 8];
            }
#pragma unroll
            for (int dt = 0; dt < 4; ++dt)
#pragma unroll
                for (int nq = 0; nq < 4; ++nq)
                    oacc[dt][nq] = __builtin_amdgcn_mfma_f32_16x16x32_bf16(
                        vf[dt], pf[nq], oacc[dt][nq], 0, 0, 0);
        }
    }

#pragma unroll
    for (int nq = 0; nq < 4; ++nq) {
        float inv = 1.f / lsum[nq];
        size_t rbase = ((size_t)b * SS + qt * 64 + nq * 16 + c16) * DD + h * HDIM;
#pragma unroll
        for (int dt = 0; dt < 4; ++dt) {
            union { ushort u[4]; uint2 d; } t;
#pragma unroll
            for (int r = 0; r < 4; ++r) t.u[r] = f2bf(oacc[dt][nq][r] * inv);
            *(uint2*)(out + rbase + dt * 16 + quad * 4) = t.d;
        }
    }
}

// ---------------------------------------------------------------------------
// out = LayerNorm(a + res) * g + b    (one block per row of D=1024)
// Fully vectorized loads/stores (G13): bf16 as uint2, f32 as float4.
// ---------------------------------------------------------------------------
__device__ __forceinline__ void ldv4(const float* p, float* o) {
    float4 v = *(const float4*)p;
    o[0] = v.x; o[1] = v.y; o[2] = v.z; o[3] = v.w;
}
__device__ __forceinline__ void ldv4(const ushort* p, float* o) {
    union { ushort u[4]; uint2 d; } t;
    t.d = *(const uint2*)p;
#pragma unroll
    for (int e = 0; e < 4; ++e) o[e] = bf2f(t.u[e]);
}
__device__ __forceinline__ void stv4(float* p, const float* v) {
    float4 t; t.x = v[0]; t.y = v[1]; t.z = v[2]; t.w = v[3];
    *(float4*)p = t;
}
__device__ __forceinline__ void stv4(ushort* p, const float* v) {
    union { ushort u[4]; uint2 d; } t;
#pragma unroll
    for (int e = 0; e < 4; ++e) t.u[e] = f2bf(v[e]);
    *(uint2*)p = t.d;
}

template <typename RT, typename OT>
__global__ __launch_bounds__(256) void add_ln(
    const ushort* __restrict__ a, const RT* __restrict__ res,
    const float* __restrict__ g, const float* __restrict__ bb,
    OT* __restrict__ out)
{
    const int row = blockIdx.x;
    const int tid = threadIdx.x;
    const size_t base = (size_t)row * DD + tid * 4;

    float av[4], rv[4], x[4];
    ldv4(a + base, av);
    ldv4(res + base, rv);
    float s1 = 0.f, s2 = 0.f;
#pragma unroll
    for (int e = 0; e < 4; ++e) {
        x[e] = av[e] + rv[e];
        s1 += x[e];
        s2 += x[e] * x[e];
    }
#pragma unroll
    for (int off = 32; off > 0; off >>= 1) {
        s1 += __shfl_down(s1, off, 64);
        s2 += __shfl_down(s2, off, 64);
    }
    __shared__ float r1[4], r2[4];
    const int wave = tid >> 6, lane = tid & 63;
    if (lane == 0) { r1[wave] = s1; r2[wave] = s2; }
    __syncthreads();
    float t1 = r1[0] + r1[1] + r1[2] + r1[3];
    float t2 = r2[0] + r2[1] + r2[2] + r2[3];
    float mu  = t1 * (1.f / DD);
    float var = t2 * (1.f / DD) - mu * mu;
    float rs  = rsqrtf(var + 1e-5f);

    float gv[4], bv[4], y[4];
    ldv4(g + (size_t)tid * 4, gv);
    ldv4(bb + (size_t)tid * 4, bv);
#pragma unroll
    for (int e = 0; e < 4; ++e)
        y[e] = (x[e] - mu) * rs * gv[e] + bv[e];
    stv4(out + base, y);
}

// ---------------------------------------------------------------------------
extern "C" void kernel_launch(void* const* d_in, const int* in_sizes, int n_in,
                              void* d_out, int out_size, void* d_ws, size_t ws_size,
                              hipStream_t stream)
{
    (void)in_sizes; (void)n_in; (void)out_size; (void)ws_size;

    const float* x  = (const float*)d_in[0];
    const float* Wq = (const float*)d_in[1];
    const float* bq = (const float*)d_in[2];
    const float* Wk = (const float*)d_in[3];
    const float* bk = (const float*)d_in[4];
    const float* Wv = (const float*)d_in[5];
    const float* bv = (const float*)d_in[6];
    const float* Wo = (const float*)d_in[7];
    const float* bo = (const float*)d_in[8];
    const float* g1 = (const float*)d_in[9];
    const float* b1 = (const float*)d_in[10];
    const float* W1 = (const float*)d_in[11];
    const float* c1 = (const float*)d_in[12];
    const float* W2 = (const float*)d_in[13];
    const float* c2 = (const float*)d_in[14];
    const float* g2 = (const float*)d_in[15];
    const float* b2 = (const float*)d_in[16];
    float* outp = (float*)d_out;

    char* ws = (char*)d_ws;
    const size_t MB = 1024 * 1024;
    ushort* WqkvT = (ushort*)(ws);            // [  0,  6): Wq^T|Wk^T|Wv^T
    ushort* WoT = (ushort*)(ws + 6  * MB);    // [  6,  8)
    ushort* W1t = (ushort*)(ws + 8  * MB);    // [  8, 16)
    ushort* W2t = (ushort*)(ws + 16 * MB);    // [ 16, 24)
    ushort* xb  = (ushort*)(ws + 24 * MB);    // [ 24, 40)
    ushort* qb  = (ushort*)(ws + 40 * MB);    // [ 40, 56)
    ushort* kb  = (ushort*)(ws + 56 * MB);    // [ 56, 72)
    ushort* vT  = (ushort*)(ws + 72 * MB);    // [ 72, 88)  [b][h][64][4096]
    ushort* att = (ushort*)(ws + 88 * MB);    // [ 88,104)
    ushort* aproj = qb;
    ushort* hbuf  = att;
    ushort* m1  = (ushort*)(ws + 24 * MB);    // [ 24, 88)
    ushort* fbuf = (ushort*)(ws + 104 * MB);  // [104,120)

    dim3 blk(256, 1, 1);
    dim3 blk512(512, 1, 1);
    dim3 gQKV1((3 * DD / 128) * (MROWS / 128), 1, 1); // 1536 blocks
    dim3 ga(SS / 64, HH, BB);
    dim3 gl(MROWS, 1, 1);

    hipLaunchKernelGGL(cvt_transpose_all, dim3(128, 32, 6), blk, 0, stream,
                       Wq, Wk, Wv, Wo, W1, W2, WqkvT, WoT, W1t, W2t);
    hipLaunchKernelGGL(cvt_f32_bf16, dim3(8192), blk, 0, stream, x, xb);

    hipLaunchKernelGGL(gemm_qkv, gQKV1, blk, 0, stream, xb, WqkvT, bq, bk, bv, qb, kb, vT);

    hipLaunchKernelGGL(attn_flash, ga, dim3(64, 1, 1), 0, stream, qb, kb, vT, att);

    // Wo projection: M=8192, N=1024, K=1024 -> 64 x 4 = 256 blocks
    hipLaunchKernelGGL(gemm_pl, dim3(256), blk512, 0, stream,
                       att, WoT, bo, aproj, MROWS, DD, DD, 0);
    hipLaunchKernelGGL((add_ln<float, ushort>), gl, blk, 0, stream, aproj, x, g1, b1, hbuf);

    // FFN1: M=8192, N=4096, K=1024 -> 64 x 16 = 1024 blocks
    hipLaunchKernelGGL(gemm_pl, dim3(1024), blk512, 0, stream,
                       hbuf, W1t, c1, m1, MROWS, FF, DD, 1);
    // FFN2: M=8192, N=1024, K=4096 -> 64 x 4 = 256 blocks
    hipLaunchKernelGGL(gemm_pl, dim3(256), blk512, 0, stream,
                       m1, W2t, c2, fbuf, MROWS, DD, FF, 0);
    hipLaunchKernelGGL((add_ln<ushort, float>), gl, blk, 0, stream, fbuf, hbuf, g2, b2, outp);
}

// Round 6
// 535.957 us; speedup vs baseline: 1.0078x; 1.0078x over previous
//
#include <hip/hip_runtime.h>
#include <hip/hip_bf16.h>

#define BB 2
#define SS 4096
#define DD 1024
#define HH 16
#define WW 256
#define FF 4096
#define HDIM 64
#define NBLK (SS / WW)       /* 16 */
#define MROWS (BB * SS)      /* 8192 */

typedef short bfrag8 __attribute__((ext_vector_type(8)));
typedef float floatx4 __attribute__((ext_vector_type(4)));

__device__ __forceinline__ float bf2f(ushort u) {
    union { uint i; float f; } c; c.i = ((uint)u) << 16; return c.f;
}
__device__ __forceinline__ ushort f2bf(float f) {
    union { float f; uint i; } c; c.f = f;
    uint r = (c.i + 0x7FFFu + ((c.i >> 16) & 1u)) >> 16;
    return (ushort)r;
}
// gelu(tanh approx) == x * sigmoid(2z), z = 0.79788456(x + 0.044715 x^3)
__device__ __forceinline__ float gelu_fast(float x) {
    float z2 = 1.5957691216057308f * x * (1.f + 0.044715f * x * x); // 2z
    return x / (1.f + __expf(-z2));
}

// async global->LDS, 16B per lane. LDS dest must be contiguous in lane order.
__device__ __forceinline__ void gload_lds16(const ushort* g, ushort* l) {
    __builtin_amdgcn_global_load_lds(
        (const __attribute__((address_space(1))) void*)g,
        (__attribute__((address_space(3))) void*)l, 16, 0, 0);
}

#define BAR() __builtin_amdgcn_s_barrier()
#define SCHED0() __builtin_amdgcn_sched_barrier(0)
#define LGKM0() do { asm volatile("s_waitcnt lgkmcnt(0)" ::: "memory"); \
                     __builtin_amdgcn_sched_barrier(0); } while (0)

// ---------------------------------------------------------------------------
// f32 -> bf16 bulk convert (grid * 1024 elements)
// ---------------------------------------------------------------------------
__global__ __launch_bounds__(256) void cvt_f32_bf16(
    const float* __restrict__ in, ushort* __restrict__ out)
{
    size_t i = ((size_t)blockIdx.x * 256 + threadIdx.x) * 4;
    float4 v = *(const float4*)(in + i);
    union { ushort u[4]; uint2 d; } t;
    t.u[0] = f2bf(v.x); t.u[1] = f2bf(v.y);
    t.u[2] = f2bf(v.z); t.u[3] = f2bf(v.w);
    *(uint2*)(out + i) = t.d;
}

// ---------------------------------------------------------------------------
// Fused transpose-convert of ALL weights: f32 [K][N] -> bf16 [N][K].
// grid = (128, 32, 6); z selects the weight. 32x32 LDS tiles.
// ---------------------------------------------------------------------------
__global__ __launch_bounds__(256) void cvt_transpose_all(
    const float* __restrict__ Wq, const float* __restrict__ Wk,
    const float* __restrict__ Wv, const float* __restrict__ Wo,
    const float* __restrict__ W1, const float* __restrict__ W2,
    ushort* __restrict__ WqkvT, ushort* __restrict__ WoT,
    ushort* __restrict__ W1t, ushort* __restrict__ W2t)
{
    __shared__ ushort sT[32][33];
    const int z = blockIdx.z;
    const float* in; ushort* out; int K, N, n0, k0;
    if (z < 4) {
        if (blockIdx.x >= 32) return;
        in  = (z == 0) ? Wq : (z == 1) ? Wk : (z == 2) ? Wv : Wo;
        out = (z < 3) ? WqkvT + (size_t)z * 1024 * 1024 : WoT;
        K = 1024; N = 1024;
        n0 = blockIdx.x * 32; k0 = blockIdx.y * 32;
    } else if (z == 4) {
        in = W1; out = W1t; K = 1024; N = 4096;
        n0 = blockIdx.x * 32; k0 = blockIdx.y * 32;
    } else {
        in = W2; out = W2t; K = 4096; N = 1024;
        n0 = blockIdx.y * 32; k0 = blockIdx.x * 32;
    }

    const int r  = threadIdx.x >> 3;        // 0..31
    const int c4 = (threadIdx.x & 7) * 4;   // 0..28

    float4 v = *(const float4*)(in + (size_t)(k0 + r) * N + n0 + c4);
    sT[c4 + 0][r] = f2bf(v.x);
    sT[c4 + 1][r] = f2bf(v.y);
    sT[c4 + 2][r] = f2bf(v.z);
    sT[c4 + 3][r] = f2bf(v.w);
    __syncthreads();
    union { ushort u[4]; uint2 d; } t;
#pragma unroll
    for (int e = 0; e < 4; ++e) t.u[e] = sT[r][c4 + e];
    *(uint2*)(out + (size_t)(n0 + r) * K + k0 + c4) = t.d;
}

// ---------------------------------------------------------------------------
// 8-phase 256x256 GEMM (m201-faithful port, staging ledger corrected):
// C = A @ Bt^T + bias. 512 threads = 8 waves (2M x 4N), per-wave 128x64,
// BK=64, double-buffered LDS (128 KB). Per phase: {ds_reads + stage 1 unit
// -> barrier -> lgkmcnt(0) -> 16 MFMA -> barrier}. Stage order per iter:
// P0:A1(t+1) P1:A0(t+2) P2:B0(t+2) P3:B1(t+2) P4:A1(t+2) P5:A0(t+3)
// P6:B0(t+3) P7:B1(t+3)  (8 units/iter). With this order, at every P0/P4
// entry the consumed tile's 4 units are exactly the 4 oldest of 7
// outstanding -> vmcnt(6) drains precisely them; every unit gets >=4
// phases of HBM-latency cover. XOR-swizzled source cols, linear LDS dest.
// ---------------------------------------------------------------------------
__global__ __launch_bounds__(512, 1) void gemm_8ph(
    const ushort* __restrict__ A, const ushort* __restrict__ Bt,
    const float* __restrict__ bias, ushort* __restrict__ C,
    int M, int N, int K, int act)
{
    __shared__ __align__(16) ushort sA[2][256 * 64];
    __shared__ __align__(16) ushort sB[2][256 * 64];

    const int tid  = threadIdx.x;
    const int lane = tid & 63;
    const int wave = tid >> 6;
    const int wm   = (wave >> 2) * 128;
    const int wn   = (wave & 3) * 64;
    const int lrow = lane & 15;
    const int quad = lane >> 4;

    // XCD-aware bijective tile mapping (BM=BN=256)
    const int ntn = N >> 8;
    const int ntm = M >> 8;
    const int xcd = blockIdx.x & 7;
    const int idx = blockIdx.x >> 3;
    int mi, ni;
    if ((ntn & 7) == 0) { const int nb = ntn >> 3; ni = xcd * nb + idx % nb; mi = idx / nb; }
    else                { ni = idx % ntn; mi = xcd * (ntm >> 3) + idx / ntn; }
    const int m0 = mi * 256, n0 = ni * 256;

    floatx4 acc[8][4];
#pragma unroll
    for (int i = 0; i < 8; ++i)
#pragma unroll
        for (int j = 0; j < 4; ++j)
            acc[i][j] = (floatx4){0.f, 0.f, 0.f, 0.f};

    // staging geometry: one 16KB unit per phase (128 rows x 64 cols),
    // 2 x gload_lds16 per thread. Source column XOR-swizzle (self-inverse),
    // LDS dest linear in lane order (wave-uniform base + lane*16).
    // A-unit u: rows [u*64,(u+1)*64) U [128+u*64,128+(u+1)*64)
    // B-unit v: rows v*32 + {[0,32) U [64,96)} per 128-half
    const int scol = ((tid ^ (tid >> 3)) & 7) << 3;
    const int arow0 = tid >> 3;                               // A row-in-unit
    const int brow0 = ((tid >> 8) << 6) + ((tid >> 3) & 31);  // B row-in-unit

    auto stageA = [&](int buf, int u, int kofs) {
#pragma unroll
        for (int it = 0; it < 2; ++it) {
            int gr = it * 128 + u * 64 + arow0;
            gload_lds16(A + (size_t)(m0 + gr) * K + kofs + scol,
                        (ushort*)&sA[buf][gr * 64 + (tid & 7) * 8]);
        }
    };
    auto stageB = [&](int buf, int v, int kofs) {
#pragma unroll
        for (int it = 0; it < 2; ++it) {
            int gr = it * 128 + v * 32 + brow0;
            gload_lds16(Bt + (size_t)(n0 + gr) * K + kofs + scol,
                        (ushort*)&sB[buf][gr * 64 + (tid & 7) * 8]);
        }
    };

    bfrag8 af[4][2];   // current A half-frags (m 0-3 or 4-7)
    bfrag8 bf[4][2];   // all B frags (n 0-3), halves loaded P0/P1

    auto readA = [&](int buf, int h) {
#pragma unroll
        for (int mf = 0; mf < 4; ++mf) {
            int row = wm + (h * 4 + mf) * 16 + lrow;
#pragma unroll
            for (int ks = 0; ks < 2; ++ks) {
                int G = ks * 4 + quad;
                af[mf][ks] = *(const bfrag8*)&sA[buf][row * 64 + (((G ^ row) & 7) << 3)];
            }
        }
    };
    auto readB = [&](int buf, int h) {
#pragma unroll
        for (int nf = 0; nf < 2; ++nf) {
            int row = wn + (h * 2 + nf) * 16 + lrow;
#pragma unroll
            for (int ks = 0; ks < 2; ++ks) {
                int G = ks * 4 + quad;
                bf[h * 2 + nf][ks] = *(const bfrag8*)&sB[buf][row * 64 + (((G ^ row) & 7) << 3)];
            }
        }
    };
    auto mfma_quad = [&](int mh, int nh) {
        __builtin_amdgcn_s_setprio(1);
#pragma unroll
        for (int mf = 0; mf < 4; ++mf)
#pragma unroll
            for (int nf = 0; nf < 2; ++nf)
#pragma unroll
                for (int ks = 0; ks < 2; ++ks)
                    acc[mh * 4 + mf][nh * 2 + nf] =
                        __builtin_amdgcn_mfma_f32_16x16x32_bf16(
                            bf[nh * 2 + nf][ks], af[mf][ks],
                            acc[mh * 4 + mf][nh * 2 + nf], 0, 0, 0);
        __builtin_amdgcn_s_setprio(0);
    };

    const int NT = K >> 6;   // even (K = 1024/4096)

    // prologue: tile0 all 4 units; tile1 units A0,B0,B1 (A1 staged at P0)
    stageA(0, 0, 0); stageB(0, 0, 0); stageB(0, 1, 0); stageA(0, 1, 0);
    stageA(1, 0, 64); stageB(1, 0, 64); stageB(1, 1, 64);

    for (int i = 0; ; ++i) {
        const int t0 = 2 * i;
        const bool more = (t0 + 2 < NT);
        const int kof1 = (t0 + 1) * 64, kof2 = (t0 + 2) * 64, kof3 = (t0 + 3) * 64;

        // ---- P0: consume tile t0 (buf0) quadrant (0,0)
        asm volatile("s_waitcnt vmcnt(6)" ::: "memory");
        BAR(); SCHED0();
        readA(0, 0); readB(0, 0);
        stageA(1, 1, kof1);                   // A-unit1 of tile t0+1
        BAR(); LGKM0();
        mfma_quad(0, 0);
        // ---- P1: quadrant (0,1)
        BAR(); SCHED0();
        readB(0, 1);
        if (more) stageA(0, 0, kof2);
        BAR(); LGKM0();
        mfma_quad(0, 1);
        // ---- P2: quadrant (1,1)
        BAR(); SCHED0();
        readA(0, 1);
        if (more) stageB(0, 0, kof2);
        BAR(); LGKM0();
        mfma_quad(1, 1);
        // ---- P3: quadrant (1,0) (register-only MFMA)
        BAR(); SCHED0();
        if (more) stageB(0, 1, kof2);
        BAR();
        mfma_quad(1, 0);
        // ---- P4: consume tile t0+1 (buf1) quadrant (0,0)
        if (more) asm volatile("s_waitcnt vmcnt(6)" ::: "memory");
        else      asm volatile("s_waitcnt vmcnt(0)" ::: "memory");
        BAR(); SCHED0();
        readA(1, 0); readB(1, 0);
        if (more) stageA(0, 1, kof2);
        BAR(); LGKM0();
        mfma_quad(0, 0);
        // ---- P5: quadrant (0,1)
        BAR(); SCHED0();
        readB(1, 1);
        if (more) stageA(1, 0, kof3);
        BAR(); LGKM0();
        mfma_quad(0, 1);
        // ---- P6: quadrant (1,1)
        BAR(); SCHED0();
        readA(1, 1);
        if (more) stageB(1, 0, kof3);
        BAR(); LGKM0();
        mfma_quad(1, 1);
        // ---- P7: quadrant (1,0)
        BAR(); SCHED0();
        if (more) stageB(1, 1, kof3);
        BAR();
        mfma_quad(1, 0);
        if (!more) break;
    }

    // epilogue: row = m0+wm+mt*16+lrow, col-chunk = n0+wn+nt*16+quad*4
#pragma unroll
    for (int nt = 0; nt < 4; ++nt) {
        int nb = n0 + wn + nt * 16 + quad * 4;
        union { float4 v; float f[4]; } b4;
        b4.v = *(const float4*)(bias + nb);
#pragma unroll
        for (int mt = 0; mt < 8; ++mt) {
            int row = m0 + wm + mt * 16 + lrow;
            union { ushort u[4]; uint2 d; } t;
#pragma unroll
            for (int r = 0; r < 4; ++r) {
                float v = acc[mt][nt][r] + b4.f[r];
                if (act) v = gelu_fast(v);
                t.u[r] = f2bf(v);
            }
            *(uint2*)(C + (size_t)row * N + nb) = t.d;
        }
    }
}

// ---------------------------------------------------------------------------
// GEMM: C[M,N] = A[M,K] @ B[K,N] + bias[N], Bt = B^T [N][K] bf16.
// Verified 2-phase 128x128 tile, BK=64, global_load_lds width-16 staging,
// XOR-swizzled k-granules, XCD-aware 1D grid.
// ---------------------------------------------------------------------------
__global__ __launch_bounds__(256) void gemm_bt(
    const ushort* __restrict__ A, const ushort* __restrict__ Bt,
    const float* __restrict__ bias, ushort* __restrict__ C,
    int M, int N, int K, int act)
{
    __shared__ ushort sA[128 * 64];
    __shared__ ushort sB[128 * 64];

    const int tid  = threadIdx.x;
    const int nx   = N >> 7;
    const int nyg  = (M >> 7) >> 3;          // y-panels per XCD
    const int gid  = blockIdx.x;
    const int j    = gid >> 3;
    const int m0   = ((gid & 7) * nyg + j / nx) * 128;
    const int n0   = (j % nx) * 128;
    const int wave = tid >> 6;
    const int lane = tid & 63;
    const int wm   = (wave >> 1) * 64;
    const int wn   = (wave & 1) * 64;
    const int lrow = lane & 15;
    const int quad = lane >> 4;

    floatx4 acc[4][4];
#pragma unroll
    for (int i = 0; i < 4; ++i)
#pragma unroll
        for (int j2 = 0; j2 < 4; ++j2)
            acc[i][j2] = (floatx4){0.f, 0.f, 0.f, 0.f};

    for (int k0 = 0; k0 < K; k0 += 64) {
#pragma unroll
        for (int it = 0; it < 4; ++it) {
            int c    = it * 256 + tid;            // 0..1023 chunks of 16B
            int row  = c >> 3;
            int scol = ((c ^ (row & 7)) & 7) << 3;  // XOR-swizzled source col
            gload_lds16(A  + (size_t)(m0 + row) * K + k0 + scol, &sA[c * 8]);
            gload_lds16(Bt + (size_t)(n0 + row) * K + k0 + scol, &sB[c * 8]);
        }
        __syncthreads();

#pragma unroll
        for (int ks = 0; ks < 2; ++ks) {
            bfrag8 af[4], bfv[4];
#pragma unroll
            for (int mt = 0; mt < 4; ++mt) {
                int row = wm + mt * 16 + lrow;
                int G   = ks * 4 + quad;
                af[mt] = *(const bfrag8*)&sA[row * 64 + (((G ^ row) & 7) << 3) + ((G >> 3) << 6)];
            }
#pragma unroll
            for (int nt = 0; nt < 4; ++nt) {
                int row = wn + nt * 16 + lrow;
                int G   = ks * 4 + quad;
                bfv[nt] = *(const bfrag8*)&sB[row * 64 + (((G ^ row) & 7) << 3) + ((G >> 3) << 6)];
            }
#pragma unroll
            for (int mt = 0; mt < 4; ++mt)
#pragma unroll
                for (int nt = 0; nt < 4; ++nt)
                    acc[mt][nt] = __builtin_amdgcn_mfma_f32_16x16x32_bf16(
                        bfv[nt], af[mt], acc[mt][nt], 0, 0, 0);
        }
        __syncthreads();
    }

    // epilogue: m = m0+wm+mt*16+lrow (lane), n-chunk = n0+wn+nt*16+quad*4 (regs)
#pragma unroll
    for (int nt = 0; nt < 4; ++nt) {
        int nb = n0 + wn + nt * 16 + quad * 4;
        union { float4 v; float f[4]; } b4;
        b4.v = *(const float4*)(bias + nb);
#pragma unroll
        for (int mt = 0; mt < 4; ++mt) {
            int row = m0 + wm + mt * 16 + lrow;
            union { ushort u[4]; uint2 d; } t;
#pragma unroll
            for (int r = 0; r < 4; ++r) {
                float v = acc[mt][nt][r] + b4.f[r];
                if (act) v = gelu_fast(v);
                t.u[r] = f2bf(v);
            }
            *(uint2*)(C + (size_t)row * N + nb) = t.d;
        }
    }
}

// ---------------------------------------------------------------------------
// Fused QKV GEMM (verified 2-phase 128x128): A[8192][1024] @ [Wq|Wk|Wv]
// (Bt = [3072][1024]), BK=64, swizzled staging, XCD-aware 1D grid
// (1536 blocks). cols [0,1024) -> qb; [1024,2048) -> kb;
// [2048,3072) -> vT [b][h][dh][s] (swapped-operand MFMA).
// ---------------------------------------------------------------------------
__global__ __launch_bounds__(256) void gemm_qkv(
    const ushort* __restrict__ A, const ushort* __restrict__ Bt,
    const float* __restrict__ bq, const float* __restrict__ bk,
    const float* __restrict__ bv,
    ushort* __restrict__ qb, ushort* __restrict__ kb, ushort* __restrict__ vT)
{
    __shared__ ushort sA[128 * 64];
    __shared__ ushort sB[128 * 64];
    const int K = DD;

    const int tid  = threadIdx.x;
    const int nx   = 24, nyg = 8;
    const int gid  = blockIdx.x;
    const int j    = gid >> 3;
    const int m0   = ((gid & 7) * nyg + j / nx) * 128;
    const int n0   = (j % nx) * 128;
    const int wave = tid >> 6;
    const int lane = tid & 63;
    const int wm   = (wave >> 1) * 64;
    const int wn   = (wave & 1) * 64;
    const int lrow = lane & 15;
    const int quad = lane >> 4;
    const int sel  = n0 >> 10;               // block-uniform: 0=q 1=k 2=v

    floatx4 acc[4][4];
#pragma unroll
    for (int i = 0; i < 4; ++i)
#pragma unroll
        for (int j2 = 0; j2 < 4; ++j2)
            acc[i][j2] = (floatx4){0.f, 0.f, 0.f, 0.f};

    for (int k0 = 0; k0 < K; k0 += 64) {
#pragma unroll
        for (int it = 0; it < 4; ++it) {
            int c    = it * 256 + tid;
            int row  = c >> 3;
            int scol = ((c ^ (row & 7)) & 7) << 3;
            gload_lds16(A  + (size_t)(m0 + row) * K + k0 + scol, &sA[c * 8]);
            gload_lds16(Bt + (size_t)(n0 + row) * K + k0 + scol, &sB[c * 8]);
        }
        __syncthreads();

#pragma unroll
        for (int ks = 0; ks < 2; ++ks) {
            bfrag8 af[4], bfv[4];
#pragma unroll
            for (int mt = 0; mt < 4; ++mt) {
                int row = wm + mt * 16 + lrow;
                int G   = ks * 4 + quad;
                af[mt] = *(const bfrag8*)&sA[row * 64 + (((G ^ row) & 7) << 3)];
            }
#pragma unroll
            for (int nt = 0; nt < 4; ++nt) {
                int row = wn + nt * 16 + lrow;
                int G   = ks * 4 + quad;
                bfv[nt] = *(const bfrag8*)&sB[row * 64 + (((G ^ row) & 7) << 3)];
            }
            if (sel < 2) {
#pragma unroll
                for (int mt = 0; mt < 4; ++mt)
#pragma unroll
                    for (int nt = 0; nt < 4; ++nt)
                        acc[mt][nt] = __builtin_amdgcn_mfma_f32_16x16x32_bf16(
                            bfv[nt], af[mt], acc[mt][nt], 0, 0, 0);
            } else {
#pragma unroll
                for (int mt = 0; mt < 4; ++mt)
#pragma unroll
                    for (int nt = 0; nt < 4; ++nt)
                        acc[mt][nt] = __builtin_amdgcn_mfma_f32_16x16x32_bf16(
                            af[mt], bfv[nt], acc[mt][nt], 0, 0, 0);
            }
        }
        __syncthreads();
    }

    if (sel < 2) {
        ushort* C = (sel == 0) ? qb : kb;
        const float* bias = (sel == 0) ? bq : bk;
        const int colbase = n0 + wn;
#pragma unroll
        for (int nt = 0; nt < 4; ++nt) {
            int nb = (colbase + nt * 16 + quad * 4) & 1023;
            union { float4 v; float f[4]; } b4;
            b4.v = *(const float4*)(bias + nb);
#pragma unroll
            for (int mt = 0; mt < 4; ++mt) {
                int row = m0 + wm + mt * 16 + lrow;
                union { ushort u[4]; uint2 d; } t;
#pragma unroll
                for (int r = 0; r < 4; ++r) t.u[r] = f2bf(acc[mt][nt][r] + b4.f[r]);
                *(uint2*)(C + (size_t)row * DD + nb) = t.d;
            }
        }
    } else {
        const int colbase = n0 + wn;
#pragma unroll
        for (int nt = 0; nt < 4; ++nt) {
            int cc = (colbase + nt * 16 + lrow) & 1023;
            int h = cc >> 6, dh = cc & 63;
            float bb = bv[cc];
#pragma unroll
            for (int mt = 0; mt < 4; ++mt) {
                int row0 = m0 + wm + mt * 16 + (quad << 2);
                int b = row0 >> 12, s = row0 & 4095;
                union { ushort u[4]; uint2 d; } t;
#pragma unroll
                for (int r = 0; r < 4; ++r) t.u[r] = f2bf(acc[mt][nt][r] + bb);
                *(uint2*)(vT + (size_t)(((b * HH + h) * HDIM + dh)) * SS + s) = t.d;
            }
        }
    }
}

// ---------------------------------------------------------------------------
// Barrier-free MFMA flash attention. One wave per block; block = (qt, h, b).
// S^T = K·Q^T -> online softmax -> P via swizzled LDS -> O^T += V^T·P^T
// (V^T straight from global vT). No __syncthreads.
// ---------------------------------------------------------------------------
__global__ __launch_bounds__(64, 2) void attn_flash(
    const ushort* __restrict__ q, const ushort* __restrict__ k,
    const ushort* __restrict__ vT, ushort* __restrict__ out)
{
    __shared__ ushort sP[64 * 72];

    const int qt = blockIdx.x, h = blockIdx.y, b = blockIdx.z;
    const int lane = threadIdx.x;
    const int c16  = lane & 15;
    const int quad = lane >> 4;
    const float CC = 0.18033688011112042f;   // (1/sqrt(64)) * log2(e)

    bfrag8 qf[4][2];
    {
        const size_t qbase = ((size_t)b * SS + qt * 64) * DD + h * HDIM;
#pragma unroll
        for (int nt = 0; nt < 4; ++nt)
#pragma unroll
            for (int ks = 0; ks < 2; ++ks)
                qf[nt][ks] = *(const bfrag8*)(q + qbase +
                    (size_t)(nt * 16 + c16) * DD + ks * 32 + quad * 8);
    }

    floatx4 oacc[4][4];
#pragma unroll
    for (int i = 0; i < 4; ++i)
#pragma unroll
        for (int j = 0; j < 4; ++j)
            oacc[i][j] = (floatx4){0.f, 0.f, 0.f, 0.f};
    float mrow[4], lsum[4];
#pragma unroll
    for (int i = 0; i < 4; ++i) { mrow[i] = -1e30f; lsum[i] = 0.f; }

    const int st0 = (qt - 4 > 0) ? qt - 4 : 0;
    const int st1 = (qt + 4 < 63) ? qt + 4 : 63;
    const size_t kb_b  = (size_t)b * SS * DD + h * HDIM;
    const size_t vT_b  = (size_t)((b * HH + h) * HDIM) * SS;

    for (int st = st0; st <= st1; ++st) {
        const int dlt = st - qt;

        floatx4 sacc[4][4];
#pragma unroll
        for (int i = 0; i < 4; ++i)
#pragma unroll
            for (int j = 0; j < 4; ++j)
                sacc[i][j] = (floatx4){0.f, 0.f, 0.f, 0.f};
#pragma unroll
        for (int ks = 0; ks < 2; ++ks) {
            bfrag8 kf[4];
#pragma unroll
            for (int mt = 0; mt < 4; ++mt)
                kf[mt] = *(const bfrag8*)(k + kb_b +
                    (size_t)(st * 64 + mt * 16 + c16) * DD + ks * 32 + quad * 8);
#pragma unroll
            for (int mt = 0; mt < 4; ++mt)
#pragma unroll
                for (int nt = 0; nt < 4; ++nt)
                    sacc[mt][nt] = __builtin_amdgcn_mfma_f32_16x16x32_bf16(
                        kf[mt], qf[nt][ks], sacc[mt][nt], 0, 0, 0);
        }

        if (dlt == 4 || dlt == -4) {
#pragma unroll
            for (int mt = 0; mt < 4; ++mt)
#pragma unroll
                for (int nt = 0; nt < 4; ++nt)
#pragma unroll
                    for (int r = 0; r < 4; ++r) {
                        int kl = mt * 16 + quad * 4 + r;
                        int ql = nt * 16 + c16;
                        bool ok = (dlt < 0) ? (kl >= ql) : (kl <= ql);
                        if (!ok) sacc[mt][nt][r] = -1e30f;
                    }
        }

        float pm[4];
#pragma unroll
        for (int nt = 0; nt < 4; ++nt) {
            float a0 = fmaxf(fmaxf(sacc[0][nt][0], sacc[0][nt][1]),
                             fmaxf(sacc[0][nt][2], sacc[0][nt][3]));
            float a1 = fmaxf(fmaxf(sacc[1][nt][0], sacc[1][nt][1]),
                             fmaxf(sacc[1][nt][2], sacc[1][nt][3]));
            float a2 = fmaxf(fmaxf(sacc[2][nt][0], sacc[2][nt][1]),
                             fmaxf(sacc[2][nt][2], sacc[2][nt][3]));
            float a3 = fmaxf(fmaxf(sacc[3][nt][0], sacc[3][nt][1]),
                             fmaxf(sacc[3][nt][2], sacc[3][nt][3]));
            pm[nt] = fmaxf(fmaxf(a0, a1), fmaxf(a2, a3));
            pm[nt] = fmaxf(pm[nt], __shfl_xor(pm[nt], 16, 64));
            pm[nt] = fmaxf(pm[nt], __shfl_xor(pm[nt], 32, 64));
        }
        float al[4];
#pragma unroll
        for (int nt = 0; nt < 4; ++nt) {
            float mn = fmaxf(mrow[nt], pm[nt]);
            al[nt] = exp2f((mrow[nt] - mn) * CC);
            mrow[nt] = mn;
        }
        float ps[4] = {0.f, 0.f, 0.f, 0.f};
#pragma unroll
        for (int mt = 0; mt < 4; ++mt)
#pragma unroll
            for (int nt = 0; nt < 4; ++nt)
#pragma unroll
                for (int r = 0; r < 4; ++r) {
                    float p = exp2f((sacc[mt][nt][r] - mrow[nt]) * CC);
                    sacc[mt][nt][r] = p;
                    ps[nt] += p;
                }
#pragma unroll
        for (int nt = 0; nt < 4; ++nt) {
            ps[nt] += __shfl_xor(ps[nt], 16, 64);
            ps[nt] += __shfl_xor(ps[nt], 32, 64);
            lsum[nt] = lsum[nt] * al[nt] + ps[nt];
        }

#pragma unroll
        for (int mt = 0; mt < 4; ++mt)
#pragma unroll
            for (int nt = 0; nt < 4; ++nt) {
                int row = nt * 16 + c16;
                int g   = (2 * mt + (quad >> 1)) ^ (row & 3);
                union { ushort u[4]; uint2 d; } t;
#pragma unroll
                for (int r = 0; r < 4; ++r) t.u[r] = f2bf(sacc[mt][nt][r]);
                *(uint2*)&sP[row * 72 + g * 8 + (quad & 1) * 4] = t.d;
            }

#pragma unroll
        for (int dt = 0; dt < 4; ++dt)
#pragma unroll
            for (int nq = 0; nq < 4; ++nq)
#pragma unroll
                for (int r = 0; r < 4; ++r)
                    oacc[dt][nq][r] *= al[nq];

#pragma unroll
        for (int ks = 0; ks < 2; ++ks) {
            bfrag8 vf[4], pf[4];
#pragma unroll
            for (int dt = 0; dt < 4; ++dt)
                vf[dt] = *(const bfrag8*)(vT + vT_b +
                    (size_t)(dt * 16 + c16) * SS + st * 64 + ks * 32 + quad * 8);
#pragma unroll
            for (int nq = 0; nq < 4; ++nq) {
                int row = nq * 16 + c16;
                int g   = (4 * ks + quad) ^ (row & 3);
                pf[nq] = *(const bfrag8*)&sP[row * 72 + g * 8];
            }
#pragma unroll
            for (int dt = 0; dt < 4; ++dt)
#pragma unroll
                for (int nq = 0; nq < 4; ++nq)
                    oacc[dt][nq] = __builtin_amdgcn_mfma_f32_16x16x32_bf16(
                        vf[dt], pf[nq], oacc[dt][nq], 0, 0, 0);
        }
    }

#pragma unroll
    for (int nq = 0; nq < 4; ++nq) {
        float inv = 1.f / lsum[nq];
        size_t rbase = ((size_t)b * SS + qt * 64 + nq * 16 + c16) * DD + h * HDIM;
#pragma unroll
        for (int dt = 0; dt < 4; ++dt) {
            union { ushort u[4]; uint2 d; } t;
#pragma unroll
            for (int r = 0; r < 4; ++r) t.u[r] = f2bf(oacc[dt][nq][r] * inv);
            *(uint2*)(out + rbase + dt * 16 + quad * 4) = t.d;
        }
    }
}

// ---------------------------------------------------------------------------
// out = LayerNorm(a + res) * g + b    (one block per row of D=1024)
// Fully vectorized loads/stores (G13): bf16 as uint2, f32 as float4.
// ---------------------------------------------------------------------------
__device__ __forceinline__ void ldv4(const float* p, float* o) {
    float4 v = *(const float4*)p;
    o[0] = v.x; o[1] = v.y; o[2] = v.z; o[3] = v.w;
}
__device__ __forceinline__ void ldv4(const ushort* p, float* o) {
    union { ushort u[4]; uint2 d; } t;
    t.d = *(const uint2*)p;
#pragma unroll
    for (int e = 0; e < 4; ++e) o[e] = bf2f(t.u[e]);
}
__device__ __forceinline__ void stv4(float* p, const float* v) {
    float4 t; t.x = v[0]; t.y = v[1]; t.z = v[2]; t.w = v[3];
    *(float4*)p = t;
}
__device__ __forceinline__ void stv4(ushort* p, const float* v) {
    union { ushort u[4]; uint2 d; } t;
#pragma unroll
    for (int e = 0; e < 4; ++e) t.u[e] = f2bf(v[e]);
    *(uint2*)p = t.d;
}

template <typename RT, typename OT>
__global__ __launch_bounds__(256) void add_ln(
    const ushort* __restrict__ a, const RT* __restrict__ res,
    const float* __restrict__ g, const float* __restrict__ bb,
    OT* __restrict__ out)
{
    const int row = blockIdx.x;
    const int tid = threadIdx.x;
    const size_t base = (size_t)row * DD + tid * 4;

    float av[4], rv[4], x[4];
    ldv4(a + base, av);
    ldv4(res + base, rv);
    float s1 = 0.f, s2 = 0.f;
#pragma unroll
    for (int e = 0; e < 4; ++e) {
        x[e] = av[e] + rv[e];
        s1 += x[e];
        s2 += x[e] * x[e];
    }
#pragma unroll
    for (int off = 32; off > 0; off >>= 1) {
        s1 += __shfl_down(s1, off, 64);
        s2 += __shfl_down(s2, off, 64);
    }
    __shared__ float r1[4], r2[4];
    const int wave = tid >> 6, lane = tid & 63;
    if (lane == 0) { r1[wave] = s1; r2[wave] = s2; }
    __syncthreads();
    float t1 = r1[0] + r1[1] + r1[2] + r1[3];
    float t2 = r2[0] + r2[1] + r2[2] + r2[3];
    float mu  = t1 * (1.f / DD);
    float var = t2 * (1.f / DD) - mu * mu;
    float rs  = rsqrtf(var + 1e-5f);

    float gv[4], bv[4], y[4];
    ldv4(g + (size_t)tid * 4, gv);
    ldv4(bb + (size_t)tid * 4, bv);
#pragma unroll
    for (int e = 0; e < 4; ++e)
        y[e] = (x[e] - mu) * rs * gv[e] + bv[e];
    stv4(out + base, y);
}

// ---------------------------------------------------------------------------
extern "C" void kernel_launch(void* const* d_in, const int* in_sizes, int n_in,
                              void* d_out, int out_size, void* d_ws, size_t ws_size,
                              hipStream_t stream)
{
    (void)in_sizes; (void)n_in; (void)out_size; (void)ws_size;

    const float* x  = (const float*)d_in[0];
    const float* Wq = (const float*)d_in[1];
    const float* bq = (const float*)d_in[2];
    const float* Wk = (const float*)d_in[3];
    const float* bk = (const float*)d_in[4];
    const float* Wv = (const float*)d_in[5];
    const float* bv = (const float*)d_in[6];
    const float* Wo = (const float*)d_in[7];
    const float* bo = (const float*)d_in[8];
    const float* g1 = (const float*)d_in[9];
    const float* b1 = (const float*)d_in[10];
    const float* W1 = (const float*)d_in[11];
    const float* c1 = (const float*)d_in[12];
    const float* W2 = (const float*)d_in[13];
    const float* c2 = (const float*)d_in[14];
    const float* g2 = (const float*)d_in[15];
    const float* b2 = (const float*)d_in[16];
    float* outp = (float*)d_out;

    char* ws = (char*)d_ws;
    const size_t MB = 1024 * 1024;
    ushort* WqkvT = (ushort*)(ws);            // [  0,  6): Wq^T|Wk^T|Wv^T
    ushort* WoT = (ushort*)(ws + 6  * MB);    // [  6,  8)
    ushort* W1t = (ushort*)(ws + 8  * MB);    // [  8, 16)
    ushort* W2t = (ushort*)(ws + 16 * MB);    // [ 16, 24)
    ushort* xb  = (ushort*)(ws + 24 * MB);    // [ 24, 40)
    ushort* qb  = (ushort*)(ws + 40 * MB);    // [ 40, 56)
    ushort* kb  = (ushort*)(ws + 56 * MB);    // [ 56, 72)
    ushort* vT  = (ushort*)(ws + 72 * MB);    // [ 72, 88)  [b][h][64][4096]
    ushort* att = (ushort*)(ws + 88 * MB);    // [ 88,104)
    ushort* aproj = qb;
    ushort* hbuf  = att;
    ushort* m1  = (ushort*)(ws + 24 * MB);    // [ 24, 88)
    ushort* fbuf = (ushort*)(ws + 104 * MB);  // [104,120)

    dim3 blk(256, 1, 1);
    dim3 blk512(512, 1, 1);
    dim3 gD1((DD / 128) * (MROWS / 128), 1, 1);     // 512 blocks, 1D
    dim3 gQKV1((3 * DD / 128) * (MROWS / 128), 1, 1); // 1536 blocks
    dim3 ga(SS / 64, HH, BB);
    dim3 gl(MROWS, 1, 1);

    hipLaunchKernelGGL(cvt_transpose_all, dim3(128, 32, 6), blk, 0, stream,
                       Wq, Wk, Wv, Wo, W1, W2, WqkvT, WoT, W1t, W2t);
    hipLaunchKernelGGL(cvt_f32_bf16, dim3(8192), blk, 0, stream, x, xb);

    hipLaunchKernelGGL(gemm_qkv, gQKV1, blk, 0, stream, xb, WqkvT, bq, bk, bv, qb, kb, vT);

    hipLaunchKernelGGL(attn_flash, ga, dim3(64, 1, 1), 0, stream, qb, kb, vT, att);

    hipLaunchKernelGGL(gemm_bt, gD1, blk, 0, stream, att, WoT, bo, aproj, MROWS, DD, DD, 0);
    hipLaunchKernelGGL((add_ln<float, ushort>), gl, blk, 0, stream, aproj, x, g1, b1, hbuf);

    // FFN1 on the 8-phase 256x256 kernel: 32x16 = 512 blocks
    hipLaunchKernelGGL(gemm_8ph, dim3(512), blk512, 0, stream,
                       hbuf, W1t, c1, m1, MROWS, FF, DD, 1);
    hipLaunchKernelGGL(gemm_bt, gD1, blk, 0, stream, m1, W2t, c2, fbuf, MROWS, DD, FF, 0);
    hipLaunchKernelGGL((add_ln<ushort, float>), gl, blk, 0, stream, fbuf, hbuf, g2, b2, outp);
}

// Round 8
// 509.530 us; speedup vs baseline: 1.0600x; 1.0519x over previous
//
#include <hip/hip_runtime.h>
#include <hip/hip_bf16.h>

#define BB 2
#define SS 4096
#define DD 1024
#define HH 16
#define WW 256
#define FF 4096
#define HDIM 64
#define NBLK (SS / WW)       /* 16 */
#define MROWS (BB * SS)      /* 8192 */

typedef short bfrag8 __attribute__((ext_vector_type(8)));
typedef float floatx4 __attribute__((ext_vector_type(4)));

__device__ __forceinline__ float bf2f(ushort u) {
    union { uint i; float f; } c; c.i = ((uint)u) << 16; return c.f;
}
__device__ __forceinline__ ushort f2bf(float f) {
    union { float f; uint i; } c; c.f = f;
    uint r = (c.i + 0x7FFFu + ((c.i >> 16) & 1u)) >> 16;
    return (ushort)r;
}
// gelu(tanh approx) == x * sigmoid(2z), z = 0.79788456(x + 0.044715 x^3)
__device__ __forceinline__ float gelu_fast(float x) {
    float z2 = 1.5957691216057308f * x * (1.f + 0.044715f * x * x); // 2z
    return x / (1.f + __expf(-z2));
}

// async global->LDS, 16B per lane. LDS dest must be contiguous in lane order.
__device__ __forceinline__ void gload_lds16(const ushort* g, ushort* l) {
    __builtin_amdgcn_global_load_lds(
        (const __attribute__((address_space(1))) void*)g,
        (__attribute__((address_space(3))) void*)l, 16, 0, 0);
}

// ---------------------------------------------------------------------------
// f32 -> bf16 bulk convert (grid * 1024 elements)
// ---------------------------------------------------------------------------
__global__ __launch_bounds__(256) void cvt_f32_bf16(
    const float* __restrict__ in, ushort* __restrict__ out)
{
    size_t i = ((size_t)blockIdx.x * 256 + threadIdx.x) * 4;
    float4 v = *(const float4*)(in + i);
    union { ushort u[4]; uint2 d; } t;
    t.u[0] = f2bf(v.x); t.u[1] = f2bf(v.y);
    t.u[2] = f2bf(v.z); t.u[3] = f2bf(v.w);
    *(uint2*)(out + i) = t.d;
}

// ---------------------------------------------------------------------------
// Fused transpose-convert of ALL weights: f32 [K][N] -> bf16 [N][K].
// grid = (128, 32, 6); z selects the weight. 32x32 LDS tiles.
// ---------------------------------------------------------------------------
__global__ __launch_bounds__(256) void cvt_transpose_all(
    const float* __restrict__ Wq, const float* __restrict__ Wk,
    const float* __restrict__ Wv, const float* __restrict__ Wo,
    const float* __restrict__ W1, const float* __restrict__ W2,
    ushort* __restrict__ WqkvT, ushort* __restrict__ WoT,
    ushort* __restrict__ W1t, ushort* __restrict__ W2t)
{
    __shared__ ushort sT[32][33];
    const int z = blockIdx.z;
    const float* in; ushort* out; int K, N, n0, k0;
    if (z < 4) {
        if (blockIdx.x >= 32) return;
        in  = (z == 0) ? Wq : (z == 1) ? Wk : (z == 2) ? Wv : Wo;
        out = (z < 3) ? WqkvT + (size_t)z * 1024 * 1024 : WoT;
        K = 1024; N = 1024;
        n0 = blockIdx.x * 32; k0 = blockIdx.y * 32;
    } else if (z == 4) {
        in = W1; out = W1t; K = 1024; N = 4096;
        n0 = blockIdx.x * 32; k0 = blockIdx.y * 32;
    } else {
        in = W2; out = W2t; K = 4096; N = 1024;
        n0 = blockIdx.y * 32; k0 = blockIdx.x * 32;
    }

    const int r  = threadIdx.x >> 3;        // 0..31
    const int c4 = (threadIdx.x & 7) * 4;   // 0..28

    float4 v = *(const float4*)(in + (size_t)(k0 + r) * N + n0 + c4);
    sT[c4 + 0][r] = f2bf(v.x);
    sT[c4 + 1][r] = f2bf(v.y);
    sT[c4 + 2][r] = f2bf(v.z);
    sT[c4 + 3][r] = f2bf(v.w);
    __syncthreads();
    union { ushort u[4]; uint2 d; } t;
#pragma unroll
    for (int e = 0; e < 4; ++e) t.u[e] = sT[r][c4 + e];
    *(uint2*)(out + (size_t)(n0 + r) * K + k0 + c4) = t.d;
}

// ---------------------------------------------------------------------------
// GEMM: C[M,N] = A[M,K] @ B[K,N] + bias[N], Bt = B^T [N][K] bf16.
// Verified 2-phase 128x128 tile, BK=64, global_load_lds width-16 staging,
// XOR-swizzled k-granules, XCD-aware 1D grid.
// ---------------------------------------------------------------------------
__global__ __launch_bounds__(256) void gemm_bt(
    const ushort* __restrict__ A, const ushort* __restrict__ Bt,
    const float* __restrict__ bias, ushort* __restrict__ C,
    int M, int N, int K, int act)
{
    __shared__ ushort sA[128 * 64];
    __shared__ ushort sB[128 * 64];

    const int tid  = threadIdx.x;
    const int nx   = N >> 7;
    const int nyg  = (M >> 7) >> 3;          // y-panels per XCD
    const int gid  = blockIdx.x;
    const int j    = gid >> 3;
    const int m0   = ((gid & 7) * nyg + j / nx) * 128;
    const int n0   = (j % nx) * 128;
    const int wave = tid >> 6;
    const int lane = tid & 63;
    const int wm   = (wave >> 1) * 64;
    const int wn   = (wave & 1) * 64;
    const int lrow = lane & 15;
    const int quad = lane >> 4;

    floatx4 acc[4][4];
#pragma unroll
    for (int i = 0; i < 4; ++i)
#pragma unroll
        for (int j2 = 0; j2 < 4; ++j2)
            acc[i][j2] = (floatx4){0.f, 0.f, 0.f, 0.f};

    for (int k0 = 0; k0 < K; k0 += 64) {
#pragma unroll
        for (int it = 0; it < 4; ++it) {
            int c    = it * 256 + tid;            // 0..1023 chunks of 16B
            int row  = c >> 3;
            int scol = ((c ^ (row & 7)) & 7) << 3;  // XOR-swizzled source col
            gload_lds16(A  + (size_t)(m0 + row) * K + k0 + scol, &sA[c * 8]);
            gload_lds16(Bt + (size_t)(n0 + row) * K + k0 + scol, &sB[c * 8]);
        }
        __syncthreads();

#pragma unroll
        for (int ks = 0; ks < 2; ++ks) {
            bfrag8 af[4], bfv[4];
#pragma unroll
            for (int mt = 0; mt < 4; ++mt) {
                int row = wm + mt * 16 + lrow;
                int G   = ks * 4 + quad;
                af[mt] = *(const bfrag8*)&sA[row * 64 + (((G ^ row) & 7) << 3) + ((G >> 3) << 6)];
            }
#pragma unroll
            for (int nt = 0; nt < 4; ++nt) {
                int row = wn + nt * 16 + lrow;
                int G   = ks * 4 + quad;
                bfv[nt] = *(const bfrag8*)&sB[row * 64 + (((G ^ row) & 7) << 3) + ((G >> 3) << 6)];
            }
#pragma unroll
            for (int mt = 0; mt < 4; ++mt)
#pragma unroll
                for (int nt = 0; nt < 4; ++nt)
                    acc[mt][nt] = __builtin_amdgcn_mfma_f32_16x16x32_bf16(
                        bfv[nt], af[mt], acc[mt][nt], 0, 0, 0);
        }
        __syncthreads();
    }

    // epilogue: m = m0+wm+mt*16+lrow (lane), n-chunk = n0+wn+nt*16+quad*4 (regs)
#pragma unroll
    for (int nt = 0; nt < 4; ++nt) {
        int nb = n0 + wn + nt * 16 + quad * 4;
        union { float4 v; float f[4]; } b4;
        b4.v = *(const float4*)(bias + nb);
#pragma unroll
        for (int mt = 0; mt < 4; ++mt) {
            int row = m0 + wm + mt * 16 + lrow;
            union { ushort u[4]; uint2 d; } t;
#pragma unroll
            for (int r = 0; r < 4; ++r) {
                float v = acc[mt][nt][r] + b4.f[r];
                if (act) v = gelu_fast(v);
                t.u[r] = f2bf(v);
            }
            *(uint2*)(C + (size_t)row * N + nb) = t.d;
        }
    }
}

// ---------------------------------------------------------------------------
// Split-K x2 GEMM for FFN2 (M=8192, N=1024, K=4096): grid = 1024 blocks;
// lower 512 compute K [0,2048) -> C0, upper 512 compute K [2048,4096) -> C1.
// Raw partials (no bias/act), bf16. Same verified 2-phase body. Doubles
// resident blocks/CU (2 -> 4) for latency hiding.
// ---------------------------------------------------------------------------
__global__ __launch_bounds__(256) void gemm_bt_sk2(
    const ushort* __restrict__ A, const ushort* __restrict__ Bt,
    ushort* __restrict__ C0, ushort* __restrict__ C1)
{
    __shared__ ushort sA[128 * 64];
    __shared__ ushort sB[128 * 64];

    const int M = MROWS, N = DD, K = FF;
    const int tid  = threadIdx.x;
    const int nx   = N >> 7;                 // 8
    const int nyg  = (M >> 7) >> 3;          // 8
    const int half = (blockIdx.x >> 9);      // 0 or 1 (512 blocks per half)
    const int gid  = blockIdx.x & 511;
    const int ks0  = half ? (K >> 1) : 0;
    const int ks1  = ks0 + (K >> 1);
    ushort* C = half ? C1 : C0;

    const int j    = gid >> 3;
    const int m0   = ((gid & 7) * nyg + j / nx) * 128;
    const int n0   = (j % nx) * 128;
    const int wave = tid >> 6;
    const int lane = tid & 63;
    const int wm   = (wave >> 1) * 64;
    const int wn   = (wave & 1) * 64;
    const int lrow = lane & 15;
    const int quad = lane >> 4;

    floatx4 acc[4][4];
#pragma unroll
    for (int i = 0; i < 4; ++i)
#pragma unroll
        for (int j2 = 0; j2 < 4; ++j2)
            acc[i][j2] = (floatx4){0.f, 0.f, 0.f, 0.f};

    for (int k0 = ks0; k0 < ks1; k0 += 64) {
#pragma unroll
        for (int it = 0; it < 4; ++it) {
            int c    = it * 256 + tid;
            int row  = c >> 3;
            int scol = ((c ^ (row & 7)) & 7) << 3;
            gload_lds16(A  + (size_t)(m0 + row) * K + k0 + scol, &sA[c * 8]);
            gload_lds16(Bt + (size_t)(n0 + row) * K + k0 + scol, &sB[c * 8]);
        }
        __syncthreads();

#pragma unroll
        for (int ks = 0; ks < 2; ++ks) {
            bfrag8 af[4], bfv[4];
#pragma unroll
            for (int mt = 0; mt < 4; ++mt) {
                int row = wm + mt * 16 + lrow;
                int G   = ks * 4 + quad;
                af[mt] = *(const bfrag8*)&sA[row * 64 + (((G ^ row) & 7) << 3) + ((G >> 3) << 6)];
            }
#pragma unroll
            for (int nt = 0; nt < 4; ++nt) {
                int row = wn + nt * 16 + lrow;
                int G   = ks * 4 + quad;
                bfv[nt] = *(const bfrag8*)&sB[row * 64 + (((G ^ row) & 7) << 3) + ((G >> 3) << 6)];
            }
#pragma unroll
            for (int mt = 0; mt < 4; ++mt)
#pragma unroll
                for (int nt = 0; nt < 4; ++nt)
                    acc[mt][nt] = __builtin_amdgcn_mfma_f32_16x16x32_bf16(
                        bfv[nt], af[mt], acc[mt][nt], 0, 0, 0);
        }
        __syncthreads();
    }

#pragma unroll
    for (int nt = 0; nt < 4; ++nt) {
        int nb = n0 + wn + nt * 16 + quad * 4;
#pragma unroll
        for (int mt = 0; mt < 4; ++mt) {
            int row = m0 + wm + mt * 16 + lrow;
            union { ushort u[4]; uint2 d; } t;
#pragma unroll
            for (int r = 0; r < 4; ++r) t.u[r] = f2bf(acc[mt][nt][r]);
            *(uint2*)(C + (size_t)row * N + nb) = t.d;
        }
    }
}

// ---------------------------------------------------------------------------
// Fused QKV GEMM (verified 2-phase 128x128): A[8192][1024] @ [Wq|Wk|Wv]
// (Bt = [3072][1024]), BK=64, swizzled staging, XCD-aware 1D grid
// (1536 blocks). cols [0,1024) -> qb; [1024,2048) -> kb;
// [2048,3072) -> vT [b][h][dh][s] (swapped-operand MFMA).
// ---------------------------------------------------------------------------
__global__ __launch_bounds__(256) void gemm_qkv(
    const ushort* __restrict__ A, const ushort* __restrict__ Bt,
    const float* __restrict__ bq, const float* __restrict__ bk,
    const float* __restrict__ bv,
    ushort* __restrict__ qb, ushort* __restrict__ kb, ushort* __restrict__ vT)
{
    __shared__ ushort sA[128 * 64];
    __shared__ ushort sB[128 * 64];
    const int K = DD;

    const int tid  = threadIdx.x;
    const int nx   = 24, nyg = 8;
    const int gid  = blockIdx.x;
    const int j    = gid >> 3;
    const int m0   = ((gid & 7) * nyg + j / nx) * 128;
    const int n0   = (j % nx) * 128;
    const int wave = tid >> 6;
    const int lane = tid & 63;
    const int wm   = (wave >> 1) * 64;
    const int wn   = (wave & 1) * 64;
    const int lrow = lane & 15;
    const int quad = lane >> 4;
    const int sel  = n0 >> 10;               // block-uniform: 0=q 1=k 2=v

    floatx4 acc[4][4];
#pragma unroll
    for (int i = 0; i < 4; ++i)
#pragma unroll
        for (int j2 = 0; j2 < 4; ++j2)
            acc[i][j2] = (floatx4){0.f, 0.f, 0.f, 0.f};

    for (int k0 = 0; k0 < K; k0 += 64) {
#pragma unroll
        for (int it = 0; it < 4; ++it) {
            int c    = it * 256 + tid;
            int row  = c >> 3;
            int scol = ((c ^ (row & 7)) & 7) << 3;
            gload_lds16(A  + (size_t)(m0 + row) * K + k0 + scol, &sA[c * 8]);
            gload_lds16(Bt + (size_t)(n0 + row) * K + k0 + scol, &sB[c * 8]);
        }
        __syncthreads();

#pragma unroll
        for (int ks = 0; ks < 2; ++ks) {
            bfrag8 af[4], bfv[4];
#pragma unroll
            for (int mt = 0; mt < 4; ++mt) {
                int row = wm + mt * 16 + lrow;
                int G   = ks * 4 + quad;
                af[mt] = *(const bfrag8*)&sA[row * 64 + (((G ^ row) & 7) << 3)];
            }
#pragma unroll
            for (int nt = 0; nt < 4; ++nt) {
                int row = wn + nt * 16 + lrow;
                int G   = ks * 4 + quad;
                bfv[nt] = *(const bfrag8*)&sB[row * 64 + (((G ^ row) & 7) << 3)];
            }
            if (sel < 2) {
#pragma unroll
                for (int mt = 0; mt < 4; ++mt)
#pragma unroll
                    for (int nt = 0; nt < 4; ++nt)
                        acc[mt][nt] = __builtin_amdgcn_mfma_f32_16x16x32_bf16(
                            bfv[nt], af[mt], acc[mt][nt], 0, 0, 0);
            } else {
#pragma unroll
                for (int mt = 0; mt < 4; ++mt)
#pragma unroll
                    for (int nt = 0; nt < 4; ++nt)
                        acc[mt][nt] = __builtin_amdgcn_mfma_f32_16x16x32_bf16(
                            af[mt], bfv[nt], acc[mt][nt], 0, 0, 0);
            }
        }
        __syncthreads();
    }

    if (sel < 2) {
        ushort* C = (sel == 0) ? qb : kb;
        const float* bias = (sel == 0) ? bq : bk;
        const int colbase = n0 + wn;
#pragma unroll
        for (int nt = 0; nt < 4; ++nt) {
            int nb = (colbase + nt * 16 + quad * 4) & 1023;
            union { float4 v; float f[4]; } b4;
            b4.v = *(const float4*)(bias + nb);
#pragma unroll
            for (int mt = 0; mt < 4; ++mt) {
                int row = m0 + wm + mt * 16 + lrow;
                union { ushort u[4]; uint2 d; } t;
#pragma unroll
                for (int r = 0; r < 4; ++r) t.u[r] = f2bf(acc[mt][nt][r] + b4.f[r]);
                *(uint2*)(C + (size_t)row * DD + nb) = t.d;
            }
        }
    } else {
        const int colbase = n0 + wn;
#pragma unroll
        for (int nt = 0; nt < 4; ++nt) {
            int cc = (colbase + nt * 16 + lrow) & 1023;
            int h = cc >> 6, dh = cc & 63;
            float bb = bv[cc];
#pragma unroll
            for (int mt = 0; mt < 4; ++mt) {
                int row0 = m0 + wm + mt * 16 + (quad << 2);
                int b = row0 >> 12, s = row0 & 4095;
                union { ushort u[4]; uint2 d; } t;
#pragma unroll
                for (int r = 0; r < 4; ++r) t.u[r] = f2bf(acc[mt][nt][r] + bb);
                *(uint2*)(vT + (size_t)(((b * HH + h) * HDIM + dh)) * SS + s) = t.d;
            }
        }
    }
}

// ---------------------------------------------------------------------------
// Barrier-free MFMA flash attention. One wave per block; block = (qt, h, b).
// S^T = K·Q^T -> online softmax -> P via swizzled LDS -> O^T += V^T·P^T
// (V^T straight from global vT). No __syncthreads.
// ---------------------------------------------------------------------------
__global__ __launch_bounds__(64, 2) void attn_flash(
    const ushort* __restrict__ q, const ushort* __restrict__ k,
    const ushort* __restrict__ vT, ushort* __restrict__ out)
{
    __shared__ ushort sP[64 * 72];

    const int qt = blockIdx.x, h = blockIdx.y, b = blockIdx.z;
    const int lane = threadIdx.x;
    const int c16  = lane & 15;
    const int quad = lane >> 4;
    const float CC = 0.18033688011112042f;   // (1/sqrt(64)) * log2(e)

    bfrag8 qf[4][2];
    {
        const size_t qbase = ((size_t)b * SS + qt * 64) * DD + h * HDIM;
#pragma unroll
        for (int nt = 0; nt < 4; ++nt)
#pragma unroll
            for (int ks = 0; ks < 2; ++ks)
                qf[nt][ks] = *(const bfrag8*)(q + qbase +
                    (size_t)(nt * 16 + c16) * DD + ks * 32 + quad * 8);
    }

    floatx4 oacc[4][4];
#pragma unroll
    for (int i = 0; i < 4; ++i)
#pragma unroll
        for (int j = 0; j < 4; ++j)
            oacc[i][j] = (floatx4){0.f, 0.f, 0.f, 0.f};
    float mrow[4], lsum[4];
#pragma unroll
    for (int i = 0; i < 4; ++i) { mrow[i] = -1e30f; lsum[i] = 0.f; }

    const int st0 = (qt - 4 > 0) ? qt - 4 : 0;
    const int st1 = (qt + 4 < 63) ? qt + 4 : 63;
    const size_t kb_b  = (size_t)b * SS * DD + h * HDIM;
    const size_t vT_b  = (size_t)((b * HH + h) * HDIM) * SS;

    for (int st = st0; st <= st1; ++st) {
        const int dlt = st - qt;

        floatx4 sacc[4][4];
#pragma unroll
        for (int i = 0; i < 4; ++i)
#pragma unroll
            for (int j = 0; j < 4; ++j)
                sacc[i][j] = (floatx4){0.f, 0.f, 0.f, 0.f};
#pragma unroll
        for (int ks = 0; ks < 2; ++ks) {
            bfrag8 kf[4];
#pragma unroll
            for (int mt = 0; mt < 4; ++mt)
                kf[mt] = *(const bfrag8*)(k + kb_b +
                    (size_t)(st * 64 + mt * 16 + c16) * DD + ks * 32 + quad * 8);
#pragma unroll
            for (int mt = 0; mt < 4; ++mt)
#pragma unroll
                for (int nt = 0; nt < 4; ++nt)
                    sacc[mt][nt] = __builtin_amdgcn_mfma_f32_16x16x32_bf16(
                        kf[mt], qf[nt][ks], sacc[mt][nt], 0, 0, 0);
        }

        if (dlt == 4 || dlt == -4) {
#pragma unroll
            for (int mt = 0; mt < 4; ++mt)
#pragma unroll
                for (int nt = 0; nt < 4; ++nt)
#pragma unroll
                    for (int r = 0; r < 4; ++r) {
                        int kl = mt * 16 + quad * 4 + r;
                        int ql = nt * 16 + c16;
                        bool ok = (dlt < 0) ? (kl >= ql) : (kl <= ql);
                        if (!ok) sacc[mt][nt][r] = -1e30f;
                    }
        }

        float pm[4];
#pragma unroll
        for (int nt = 0; nt < 4; ++nt) {
            float a0 = fmaxf(fmaxf(sacc[0][nt][0], sacc[0][nt][1]),
                             fmaxf(sacc[0][nt][2], sacc[0][nt][3]));
            float a1 = fmaxf(fmaxf(sacc[1][nt][0], sacc[1][nt][1]),
                             fmaxf(sacc[1][nt][2], sacc[1][nt][3]));
            float a2 = fmaxf(fmaxf(sacc[2][nt][0], sacc[2][nt][1]),
                             fmaxf(sacc[2][nt][2], sacc[2][nt][3]));
            float a3 = fmaxf(fmaxf(sacc[3][nt][0], sacc[3][nt][1]),
                             fmaxf(sacc[3][nt][2], sacc[3][nt][3]));
            pm[nt] = fmaxf(fmaxf(a0, a1), fmaxf(a2, a3));
            pm[nt] = fmaxf(pm[nt], __shfl_xor(pm[nt], 16, 64));
            pm[nt] = fmaxf(pm[nt], __shfl_xor(pm[nt], 32, 64));
        }
        float al[4];
#pragma unroll
        for (int nt = 0; nt < 4; ++nt) {
            float mn = fmaxf(mrow[nt], pm[nt]);
            al[nt] = exp2f((mrow[nt] - mn) * CC);
            mrow[nt] = mn;
        }
        float ps[4] = {0.f, 0.f, 0.f, 0.f};
#pragma unroll
        for (int mt = 0; mt < 4; ++mt)
#pragma unroll
            for (int nt = 0; nt < 4; ++nt)
#pragma unroll
                for (int r = 0; r < 4; ++r) {
                    float p = exp2f((sacc[mt][nt][r] - mrow[nt]) * CC);
                    sacc[mt][nt][r] = p;
                    ps[nt] += p;
                }
#pragma unroll
        for (int nt = 0; nt < 4; ++nt) {
            ps[nt] += __shfl_xor(ps[nt], 16, 64);
            ps[nt] += __shfl_xor(ps[nt], 32, 64);
            lsum[nt] = lsum[nt] * al[nt] + ps[nt];
        }

#pragma unroll
        for (int mt = 0; mt < 4; ++mt)
#pragma unroll
            for (int nt = 0; nt < 4; ++nt) {
                int row = nt * 16 + c16;
                int g   = (2 * mt + (quad >> 1)) ^ (row & 3);
                union { ushort u[4]; uint2 d; } t;
#pragma unroll
                for (int r = 0; r < 4; ++r) t.u[r] = f2bf(sacc[mt][nt][r]);
                *(uint2*)&sP[row * 72 + g * 8 + (quad & 1) * 4] = t.d;
            }

#pragma unroll
        for (int dt = 0; dt < 4; ++dt)
#pragma unroll
            for (int nq = 0; nq < 4; ++nq)
#pragma unroll
                for (int r = 0; r < 4; ++r)
                    oacc[dt][nq][r] *= al[nq];

#pragma unroll
        for (int ks = 0; ks < 2; ++ks) {
            bfrag8 vf[4], pf[4];
#pragma unroll
            for (int dt = 0; dt < 4; ++dt)
                vf[dt] = *(const bfrag8*)(vT + vT_b +
                    (size_t)(dt * 16 + c16) * SS + st * 64 + ks * 32 + quad * 8);
#pragma unroll
            for (int nq = 0; nq < 4; ++nq) {
                int row = nq * 16 + c16;
                int g   = (4 * ks + quad) ^ (row & 3);
                pf[nq] = *(const bfrag8*)&sP[row * 72 + g * 8];
            }
#pragma unroll
            for (int dt = 0; dt < 4; ++dt)
#pragma unroll
                for (int nq = 0; nq < 4; ++nq)
                    oacc[dt][nq] = __builtin_amdgcn_mfma_f32_16x16x32_bf16(
                        vf[dt], pf[nq], oacc[dt][nq], 0, 0, 0);
        }
    }

#pragma unroll
    for (int nq = 0; nq < 4; ++nq) {
        float inv = 1.f / lsum[nq];
        size_t rbase = ((size_t)b * SS + qt * 64 + nq * 16 + c16) * DD + h * HDIM;
#pragma unroll
        for (int dt = 0; dt < 4; ++dt) {
            union { ushort u[4]; uint2 d; } t;
#pragma unroll
            for (int r = 0; r < 4; ++r) t.u[r] = f2bf(oacc[dt][nq][r] * inv);
            *(uint2*)(out + rbase + dt * 16 + quad * 4) = t.d;
        }
    }
}

// ---------------------------------------------------------------------------
// out = LayerNorm(a + res) * g + b    (one block per row of D=1024)
// Fully vectorized loads/stores (G13): bf16 as uint2, f32 as float4.
// ---------------------------------------------------------------------------
__device__ __forceinline__ void ldv4(const float* p, float* o) {
    float4 v = *(const float4*)p;
    o[0] = v.x; o[1] = v.y; o[2] = v.z; o[3] = v.w;
}
__device__ __forceinline__ void ldv4(const ushort* p, float* o) {
    union { ushort u[4]; uint2 d; } t;
    t.d = *(const uint2*)p;
#pragma unroll
    for (int e = 0; e < 4; ++e) o[e] = bf2f(t.u[e]);
}
__device__ __forceinline__ void stv4(float* p, const float* v) {
    float4 t; t.x = v[0]; t.y = v[1]; t.z = v[2]; t.w = v[3];
    *(float4*)p = t;
}
__device__ __forceinline__ void stv4(ushort* p, const float* v) {
    union { ushort u[4]; uint2 d; } t;
#pragma unroll
    for (int e = 0; e < 4; ++e) t.u[e] = f2bf(v[e]);
    *(uint2*)p = t.d;
}

template <typename RT, typename OT>
__global__ __launch_bounds__(256) void add_ln(
    const ushort* __restrict__ a, const RT* __restrict__ res,
    const float* __restrict__ g, const float* __restrict__ bb,
    OT* __restrict__ out)
{
    const int row = blockIdx.x;
    const int tid = threadIdx.x;
    const size_t base = (size_t)row * DD + tid * 4;

    float av[4], rv[4], x[4];
    ldv4(a + base, av);
    ldv4(res + base, rv);
    float s1 = 0.f, s2 = 0.f;
#pragma unroll
    for (int e = 0; e < 4; ++e) {
        x[e] = av[e] + rv[e];
        s1 += x[e];
        s2 += x[e] * x[e];
    }
#pragma unroll
    for (int off = 32; off > 0; off >>= 1) {
        s1 += __shfl_down(s1, off, 64);
        s2 += __shfl_down(s2, off, 64);
    }
    __shared__ float r1[4], r2[4];
    const int wave = tid >> 6, lane = tid & 63;
    if (lane == 0) { r1[wave] = s1; r2[wave] = s2; }
    __syncthreads();
    float t1 = r1[0] + r1[1] + r1[2] + r1[3];
    float t2 = r2[0] + r2[1] + r2[2] + r2[3];
    float mu  = t1 * (1.f / DD);
    float var = t2 * (1.f / DD) - mu * mu;
    float rs  = rsqrtf(var + 1e-5f);

    float gv[4], bv[4], y[4];
    ldv4(g + (size_t)tid * 4, gv);
    ldv4(bb + (size_t)tid * 4, bv);
#pragma unroll
    for (int e = 0; e < 4; ++e)
        y[e] = (x[e] - mu) * rs * gv[e] + bv[e];
    stv4(out + base, y);
}

// ---------------------------------------------------------------------------
// out = LayerNorm(p0 + p1 + cbias + res) * g + b   (split-K FFN2 combine)
// ---------------------------------------------------------------------------
__global__ __launch_bounds__(256) void add_ln2p(
    const ushort* __restrict__ p0, const ushort* __restrict__ p1,
    const float* __restrict__ cbias, const ushort* __restrict__ res,
    const float* __restrict__ g, const float* __restrict__ bb,
    float* __restrict__ out)
{
    const int row = blockIdx.x;
    const int tid = threadIdx.x;
    const size_t base = (size_t)row * DD + tid * 4;

    float a0[4], a1[4], cb[4], rv[4], x[4];
    ldv4(p0 + base, a0);
    ldv4(p1 + base, a1);
    ldv4(cbias + (size_t)tid * 4, cb);
    ldv4(res + base, rv);
    float s1 = 0.f, s2 = 0.f;
#pragma unroll
    for (int e = 0; e < 4; ++e) {
        x[e] = a0[e] + a1[e] + cb[e] + rv[e];
        s1 += x[e];
        s2 += x[e] * x[e];
    }
#pragma unroll
    for (int off = 32; off > 0; off >>= 1) {
        s1 += __shfl_down(s1, off, 64);
        s2 += __shfl_down(s2, off, 64);
    }
    __shared__ float r1[4], r2[4];
    const int wave = tid >> 6, lane = tid & 63;
    if (lane == 0) { r1[wave] = s1; r2[wave] = s2; }
    __syncthreads();
    float t1 = r1[0] + r1[1] + r1[2] + r1[3];
    float t2 = r2[0] + r2[1] + r2[2] + r2[3];
    float mu  = t1 * (1.f / DD);
    float var = t2 * (1.f / DD) - mu * mu;
    float rs  = rsqrtf(var + 1e-5f);

    float gv[4], bv[4], y[4];
    ldv4(g + (size_t)tid * 4, gv);
    ldv4(bb + (size_t)tid * 4, bv);
#pragma unroll
    for (int e = 0; e < 4; ++e)
        y[e] = (x[e] - mu) * rs * gv[e] + bv[e];
    stv4(out + base, y);
}

// ---------------------------------------------------------------------------
extern "C" void kernel_launch(void* const* d_in, const int* in_sizes, int n_in,
                              void* d_out, int out_size, void* d_ws, size_t ws_size,
                              hipStream_t stream)
{
    (void)in_sizes; (void)n_in; (void)out_size; (void)ws_size;

    const float* x  = (const float*)d_in[0];
    const float* Wq = (const float*)d_in[1];
    const float* bq = (const float*)d_in[2];
    const float* Wk = (const float*)d_in[3];
    const float* bk = (const float*)d_in[4];
    const float* Wv = (const float*)d_in[5];
    const float* bv = (const float*)d_in[6];
    const float* Wo = (const float*)d_in[7];
    const float* bo = (const float*)d_in[8];
    const float* g1 = (const float*)d_in[9];
    const float* b1 = (const float*)d_in[10];
    const float* W1 = (const float*)d_in[11];
    const float* c1 = (const float*)d_in[12];
    const float* W2 = (const float*)d_in[13];
    const float* c2 = (const float*)d_in[14];
    const float* g2 = (const float*)d_in[15];
    const float* b2 = (const float*)d_in[16];
    float* outp = (float*)d_out;

    char* ws = (char*)d_ws;
    const size_t MB = 1024 * 1024;
    ushort* WqkvT = (ushort*)(ws);            // [  0,  6): Wq^T|Wk^T|Wv^T
    ushort* WoT = (ushort*)(ws + 6  * MB);    // [  6,  8)
    ushort* W1t = (ushort*)(ws + 8  * MB);    // [  8, 16)
    ushort* W2t = (ushort*)(ws + 16 * MB);    // [ 16, 24)
    ushort* xb  = (ushort*)(ws + 24 * MB);    // [ 24, 40)
    ushort* qb  = (ushort*)(ws + 40 * MB);    // [ 40, 56)
    ushort* kb  = (ushort*)(ws + 56 * MB);    // [ 56, 72)
    ushort* vT  = (ushort*)(ws + 72 * MB);    // [ 72, 88)  [b][h][64][4096]
    ushort* att = (ushort*)(ws + 88 * MB);    // [ 88,104)
    ushort* aproj = qb;
    ushort* hbuf  = att;
    ushort* m1  = (ushort*)(ws + 24 * MB);    // [ 24, 88)  FFN1 out (64 MB!)
    ushort* fbuf = (ushort*)(ws + 104 * MB);  // [104,120)  split-K partial 0
    // split-K partial 1 -> [0,16): WqkvT/WoT/W1t are ALL dead by FFN2 time.
    // (NOT qb: qb = [40,56) lies INSIDE m1's [24,88) — round-7 bug.)
    ushort* part1 = (ushort*)(ws);

    dim3 blk(256, 1, 1);
    dim3 gD1((DD / 128) * (MROWS / 128), 1, 1);     // 512 blocks, 1D
    dim3 gQKV1((3 * DD / 128) * (MROWS / 128), 1, 1); // 1536 blocks
    dim3 gF1((FF / 128) * (MROWS / 128), 1, 1);     // 2048 blocks
    dim3 ga(SS / 64, HH, BB);
    dim3 gl(MROWS, 1, 1);

    hipLaunchKernelGGL(cvt_transpose_all, dim3(128, 32, 6), blk, 0, stream,
                       Wq, Wk, Wv, Wo, W1, W2, WqkvT, WoT, W1t, W2t);
    hipLaunchKernelGGL(cvt_f32_bf16, dim3(8192), blk, 0, stream, x, xb);

    hipLaunchKernelGGL(gemm_qkv, gQKV1, blk, 0, stream, xb, WqkvT, bq, bk, bv, qb, kb, vT);

    hipLaunchKernelGGL(attn_flash, ga, dim3(64, 1, 1), 0, stream, qb, kb, vT, att);

    hipLaunchKernelGGL(gemm_bt, gD1, blk, 0, stream, att, WoT, bo, aproj, MROWS, DD, DD, 0);
    hipLaunchKernelGGL((add_ln<float, ushort>), gl, blk, 0, stream, aproj, x, g1, b1, hbuf);

    hipLaunchKernelGGL(gemm_bt, gF1, blk, 0, stream, hbuf, W1t, c1, m1, MROWS, FF, DD, 1);
    // FFN2 split-K x2: 1024 blocks; partials (no bias) -> fbuf, part1
    hipLaunchKernelGGL(gemm_bt_sk2, dim3(1024), blk, 0, stream, m1, W2t, fbuf, part1);
    hipLaunchKernelGGL(add_ln2p, gl, blk, 0, stream, fbuf, part1, c2, hbuf, g2, b2, outp);
}

// Round 9
// 490.785 us; speedup vs baseline: 1.1005x; 1.0382x over previous
//
#include <hip/hip_runtime.h>
#include <hip/hip_bf16.h>

#define BB 2
#define SS 4096
#define DD 1024
#define HH 16
#define WW 256
#define FF 4096
#define HDIM 64
#define NBLK (SS / WW)       /* 16 */
#define MROWS (BB * SS)      /* 8192 */

typedef short bfrag8 __attribute__((ext_vector_type(8)));
typedef float floatx4 __attribute__((ext_vector_type(4)));

__device__ __forceinline__ float bf2f(ushort u) {
    union { uint i; float f; } c; c.i = ((uint)u) << 16; return c.f;
}
__device__ __forceinline__ ushort f2bf(float f) {
    union { float f; uint i; } c; c.f = f;
    uint r = (c.i + 0x7FFFu + ((c.i >> 16) & 1u)) >> 16;
    return (ushort)r;
}
// gelu(tanh approx) == x * sigmoid(2z), z = 0.79788456(x + 0.044715 x^3)
__device__ __forceinline__ float gelu_fast(float x) {
    float z2 = 1.5957691216057308f * x * (1.f + 0.044715f * x * x); // 2z
    return x / (1.f + __expf(-z2));
}

// async global->LDS, 16B per lane. LDS dest must be contiguous in lane order.
__device__ __forceinline__ void gload_lds16(const ushort* g, ushort* l) {
    __builtin_amdgcn_global_load_lds(
        (const __attribute__((address_space(1))) void*)g,
        (__attribute__((address_space(3))) void*)l, 16, 0, 0);
}

// ---------------------------------------------------------------------------
// f32 -> bf16 bulk convert (grid * 1024 elements)
// ---------------------------------------------------------------------------
__global__ __launch_bounds__(256) void cvt_f32_bf16(
    const float* __restrict__ in, ushort* __restrict__ out)
{
    size_t i = ((size_t)blockIdx.x * 256 + threadIdx.x) * 4;
    float4 v = *(const float4*)(in + i);
    union { ushort u[4]; uint2 d; } t;
    t.u[0] = f2bf(v.x); t.u[1] = f2bf(v.y);
    t.u[2] = f2bf(v.z); t.u[3] = f2bf(v.w);
    *(uint2*)(out + i) = t.d;
}

// ---------------------------------------------------------------------------
// Fused transpose-convert of ALL weights: f32 [K][N] -> bf16 [N][K].
// grid = (128, 32, 6); z selects the weight. 32x32 LDS tiles.
// ---------------------------------------------------------------------------
__global__ __launch_bounds__(256) void cvt_transpose_all(
    const float* __restrict__ Wq, const float* __restrict__ Wk,
    const float* __restrict__ Wv, const float* __restrict__ Wo,
    const float* __restrict__ W1, const float* __restrict__ W2,
    ushort* __restrict__ WqkvT, ushort* __restrict__ WoT,
    ushort* __restrict__ W1t, ushort* __restrict__ W2t)
{
    __shared__ ushort sT[32][33];
    const int z = blockIdx.z;
    const float* in; ushort* out; int K, N, n0, k0;
    if (z < 4) {
        if (blockIdx.x >= 32) return;
        in  = (z == 0) ? Wq : (z == 1) ? Wk : (z == 2) ? Wv : Wo;
        out = (z < 3) ? WqkvT + (size_t)z * 1024 * 1024 : WoT;
        K = 1024; N = 1024;
        n0 = blockIdx.x * 32; k0 = blockIdx.y * 32;
    } else if (z == 4) {
        in = W1; out = W1t; K = 1024; N = 4096;
        n0 = blockIdx.x * 32; k0 = blockIdx.y * 32;
    } else {
        in = W2; out = W2t; K = 4096; N = 1024;
        n0 = blockIdx.y * 32; k0 = blockIdx.x * 32;
    }

    const int r  = threadIdx.x >> 3;        // 0..31
    const int c4 = (threadIdx.x & 7) * 4;   // 0..28

    float4 v = *(const float4*)(in + (size_t)(k0 + r) * N + n0 + c4);
    sT[c4 + 0][r] = f2bf(v.x);
    sT[c4 + 1][r] = f2bf(v.y);
    sT[c4 + 2][r] = f2bf(v.z);
    sT[c4 + 3][r] = f2bf(v.w);
    __syncthreads();
    union { ushort u[4]; uint2 d; } t;
#pragma unroll
    for (int e = 0; e < 4; ++e) t.u[e] = sT[r][c4 + e];
    *(uint2*)(out + (size_t)(n0 + r) * K + k0 + c4) = t.d;
}

// ---------------------------------------------------------------------------
// GEMM: C[M,N] = A[M,K] @ B[K,N] + bias[N], Bt = B^T [N][K] bf16.
// Verified 2-phase 128x128 tile, BK=64, global_load_lds width-16 staging,
// XOR-swizzled k-granules, XCD-aware 1D grid.
// ---------------------------------------------------------------------------
__global__ __launch_bounds__(256) void gemm_bt(
    const ushort* __restrict__ A, const ushort* __restrict__ Bt,
    const float* __restrict__ bias, ushort* __restrict__ C,
    int M, int N, int K, int act)
{
    __shared__ ushort sA[128 * 64];
    __shared__ ushort sB[128 * 64];

    const int tid  = threadIdx.x;
    const int nx   = N >> 7;
    const int nyg  = (M >> 7) >> 3;          // y-panels per XCD
    const int gid  = blockIdx.x;
    const int j    = gid >> 3;
    const int m0   = ((gid & 7) * nyg + j / nx) * 128;
    const int n0   = (j % nx) * 128;
    const int wave = tid >> 6;
    const int lane = tid & 63;
    const int wm   = (wave >> 1) * 64;
    const int wn   = (wave & 1) * 64;
    const int lrow = lane & 15;
    const int quad = lane >> 4;

    floatx4 acc[4][4];
#pragma unroll
    for (int i = 0; i < 4; ++i)
#pragma unroll
        for (int j2 = 0; j2 < 4; ++j2)
            acc[i][j2] = (floatx4){0.f, 0.f, 0.f, 0.f};

    for (int k0 = 0; k0 < K; k0 += 64) {
#pragma unroll
        for (int it = 0; it < 4; ++it) {
            int c    = it * 256 + tid;            // 0..1023 chunks of 16B
            int row  = c >> 3;
            int scol = ((c ^ (row & 7)) & 7) << 3;  // XOR-swizzled source col
            gload_lds16(A  + (size_t)(m0 + row) * K + k0 + scol, &sA[c * 8]);
            gload_lds16(Bt + (size_t)(n0 + row) * K + k0 + scol, &sB[c * 8]);
        }
        __syncthreads();

#pragma unroll
        for (int ks = 0; ks < 2; ++ks) {
            bfrag8 af[4], bfv[4];
#pragma unroll
            for (int mt = 0; mt < 4; ++mt) {
                int row = wm + mt * 16 + lrow;
                int G   = ks * 4 + quad;
                af[mt] = *(const bfrag8*)&sA[row * 64 + (((G ^ row) & 7) << 3) + ((G >> 3) << 6)];
            }
#pragma unroll
            for (int nt = 0; nt < 4; ++nt) {
                int row = wn + nt * 16 + lrow;
                int G   = ks * 4 + quad;
                bfv[nt] = *(const bfrag8*)&sB[row * 64 + (((G ^ row) & 7) << 3) + ((G >> 3) << 6)];
            }
#pragma unroll
            for (int mt = 0; mt < 4; ++mt)
#pragma unroll
                for (int nt = 0; nt < 4; ++nt)
                    acc[mt][nt] = __builtin_amdgcn_mfma_f32_16x16x32_bf16(
                        bfv[nt], af[mt], acc[mt][nt], 0, 0, 0);
        }
        __syncthreads();
    }

    // epilogue: m = m0+wm+mt*16+lrow (lane), n-chunk = n0+wn+nt*16+quad*4 (regs)
#pragma unroll
    for (int nt = 0; nt < 4; ++nt) {
        int nb = n0 + wn + nt * 16 + quad * 4;
        union { float4 v; float f[4]; } b4;
        b4.v = *(const float4*)(bias + nb);
#pragma unroll
        for (int mt = 0; mt < 4; ++mt) {
            int row = m0 + wm + mt * 16 + lrow;
            union { ushort u[4]; uint2 d; } t;
#pragma unroll
            for (int r = 0; r < 4; ++r) {
                float v = acc[mt][nt][r] + b4.f[r];
                if (act) v = gelu_fast(v);
                t.u[r] = f2bf(v);
            }
            *(uint2*)(C + (size_t)row * N + nb) = t.d;
        }
    }
}

// ---------------------------------------------------------------------------
// Fused QKV GEMM (verified 2-phase 128x128): A[8192][1024] @ [Wq|Wk|Wv]
// (Bt = [3072][1024]), BK=64, swizzled staging, XCD-aware 1D grid
// (1536 blocks). cols [0,1024) -> qh [b][h][s][64]; [1024,2048) -> kh
// [b][h][s][64] (head-grouped for attn locality); [2048,3072) ->
// vT [b][h][dh][s] (swapped-operand MFMA).
// ---------------------------------------------------------------------------
__global__ __launch_bounds__(256) void gemm_qkv(
    const ushort* __restrict__ A, const ushort* __restrict__ Bt,
    const float* __restrict__ bq, const float* __restrict__ bk,
    const float* __restrict__ bv,
    ushort* __restrict__ qh, ushort* __restrict__ kh, ushort* __restrict__ vT)
{
    __shared__ ushort sA[128 * 64];
    __shared__ ushort sB[128 * 64];
    const int K = DD;

    const int tid  = threadIdx.x;
    const int nx   = 24, nyg = 8;
    const int gid  = blockIdx.x;
    const int j    = gid >> 3;
    const int m0   = ((gid & 7) * nyg + j / nx) * 128;
    const int n0   = (j % nx) * 128;
    const int wave = tid >> 6;
    const int lane = tid & 63;
    const int wm   = (wave >> 1) * 64;
    const int wn   = (wave & 1) * 64;
    const int lrow = lane & 15;
    const int quad = lane >> 4;
    const int sel  = n0 >> 10;               // block-uniform: 0=q 1=k 2=v

    floatx4 acc[4][4];
#pragma unroll
    for (int i = 0; i < 4; ++i)
#pragma unroll
        for (int j2 = 0; j2 < 4; ++j2)
            acc[i][j2] = (floatx4){0.f, 0.f, 0.f, 0.f};

    for (int k0 = 0; k0 < K; k0 += 64) {
#pragma unroll
        for (int it = 0; it < 4; ++it) {
            int c    = it * 256 + tid;
            int row  = c >> 3;
            int scol = ((c ^ (row & 7)) & 7) << 3;
            gload_lds16(A  + (size_t)(m0 + row) * K + k0 + scol, &sA[c * 8]);
            gload_lds16(Bt + (size_t)(n0 + row) * K + k0 + scol, &sB[c * 8]);
        }
        __syncthreads();

#pragma unroll
        for (int ks = 0; ks < 2; ++ks) {
            bfrag8 af[4], bfv[4];
#pragma unroll
            for (int mt = 0; mt < 4; ++mt) {
                int row = wm + mt * 16 + lrow;
                int G   = ks * 4 + quad;
                af[mt] = *(const bfrag8*)&sA[row * 64 + (((G ^ row) & 7) << 3)];
            }
#pragma unroll
            for (int nt = 0; nt < 4; ++nt) {
                int row = wn + nt * 16 + lrow;
                int G   = ks * 4 + quad;
                bfv[nt] = *(const bfrag8*)&sB[row * 64 + (((G ^ row) & 7) << 3)];
            }
            if (sel < 2) {
#pragma unroll
                for (int mt = 0; mt < 4; ++mt)
#pragma unroll
                    for (int nt = 0; nt < 4; ++nt)
                        acc[mt][nt] = __builtin_amdgcn_mfma_f32_16x16x32_bf16(
                            bfv[nt], af[mt], acc[mt][nt], 0, 0, 0);
            } else {
#pragma unroll
                for (int mt = 0; mt < 4; ++mt)
#pragma unroll
                    for (int nt = 0; nt < 4; ++nt)
                        acc[mt][nt] = __builtin_amdgcn_mfma_f32_16x16x32_bf16(
                            af[mt], bfv[nt], acc[mt][nt], 0, 0, 0);
            }
        }
        __syncthreads();
    }

    if (sel < 2) {
        ushort* C = (sel == 0) ? qh : kh;
        const float* bias = (sel == 0) ? bq : bk;
        const int colbase = n0 + wn;
#pragma unroll
        for (int nt = 0; nt < 4; ++nt) {
            int nb = (colbase + nt * 16 + quad * 4) & 1023;  // d in [0,1024)
            int h  = nb >> 6, dh = nb & 63;                  // dh <= 60
            union { float4 v; float f[4]; } b4;
            b4.v = *(const float4*)(bias + nb);
#pragma unroll
            for (int mt = 0; mt < 4; ++mt) {
                int row = m0 + wm + mt * 16 + lrow;
                int b = row >> 12, s = row & 4095;
                union { ushort u[4]; uint2 d; } t;
#pragma unroll
                for (int r = 0; r < 4; ++r) t.u[r] = f2bf(acc[mt][nt][r] + b4.f[r]);
                *(uint2*)(C + ((size_t)(b * HH + h) * SS + s) * HDIM + dh) = t.d;
            }
        }
    } else {
        const int colbase = n0 + wn;
#pragma unroll
        for (int nt = 0; nt < 4; ++nt) {
            int cc = (colbase + nt * 16 + lrow) & 1023;
            int h = cc >> 6, dh = cc & 63;
            float bb = bv[cc];
#pragma unroll
            for (int mt = 0; mt < 4; ++mt) {
                int row0 = m0 + wm + mt * 16 + (quad << 2);
                int b = row0 >> 12, s = row0 & 4095;
                union { ushort u[4]; uint2 d; } t;
#pragma unroll
                for (int r = 0; r < 4; ++r) t.u[r] = f2bf(acc[mt][nt][r] + bb);
                *(uint2*)(vT + (size_t)(((b * HH + h) * HDIM + dh)) * SS + s) = t.d;
            }
        }
    }
}

// ---------------------------------------------------------------------------
// Barrier-free MFMA flash attention. One wave per block; block = (qt, h, b).
// Q,K read from head-grouped [b][h][s][64] layout (contiguous 8KB K-tiles),
// V^T from vT [b][h][dh][s]. S^T = K·Q^T -> online softmax -> P via
// swizzled LDS -> O^T += V^T·P^T. setprio(1) around MFMA clusters (T5,
// independent-wave regime). Output written row-major [b*S+s][D] for Wo.
// ---------------------------------------------------------------------------
__global__ __launch_bounds__(64, 2) void attn_flash(
    const ushort* __restrict__ q, const ushort* __restrict__ k,
    const ushort* __restrict__ vT, ushort* __restrict__ out)
{
    __shared__ ushort sP[64 * 72];

    const int qt = blockIdx.x, h = blockIdx.y, b = blockIdx.z;
    const int lane = threadIdx.x;
    const int c16  = lane & 15;
    const int quad = lane >> 4;
    const float CC = 0.18033688011112042f;   // (1/sqrt(64)) * log2(e)

    bfrag8 qf[4][2];
    {
        const size_t qbase = ((size_t)(b * HH + h) * SS + qt * 64) * HDIM;
#pragma unroll
        for (int nt = 0; nt < 4; ++nt)
#pragma unroll
            for (int ks = 0; ks < 2; ++ks)
                qf[nt][ks] = *(const bfrag8*)(q + qbase +
                    (size_t)(nt * 16 + c16) * HDIM + ks * 32 + quad * 8);
    }

    floatx4 oacc[4][4];
#pragma unroll
    for (int i = 0; i < 4; ++i)
#pragma unroll
        for (int j = 0; j < 4; ++j)
            oacc[i][j] = (floatx4){0.f, 0.f, 0.f, 0.f};
    float mrow[4], lsum[4];
#pragma unroll
    for (int i = 0; i < 4; ++i) { mrow[i] = -1e30f; lsum[i] = 0.f; }

    const int st0 = (qt - 4 > 0) ? qt - 4 : 0;
    const int st1 = (qt + 4 < 63) ? qt + 4 : 63;
    const size_t kb_b  = (size_t)(b * HH + h) * SS * HDIM;
    const size_t vT_b  = (size_t)((b * HH + h) * HDIM) * SS;

    for (int st = st0; st <= st1; ++st) {
        const int dlt = st - qt;

        floatx4 sacc[4][4];
#pragma unroll
        for (int i = 0; i < 4; ++i)
#pragma unroll
            for (int j = 0; j < 4; ++j)
                sacc[i][j] = (floatx4){0.f, 0.f, 0.f, 0.f};
#pragma unroll
        for (int ks = 0; ks < 2; ++ks) {
            bfrag8 kf[4];
#pragma unroll
            for (int mt = 0; mt < 4; ++mt)
                kf[mt] = *(const bfrag8*)(k + kb_b +
                    (size_t)(st * 64 + mt * 16 + c16) * HDIM + ks * 32 + quad * 8);
            __builtin_amdgcn_s_setprio(1);
#pragma unroll
            for (int mt = 0; mt < 4; ++mt)
#pragma unroll
                for (int nt = 0; nt < 4; ++nt)
                    sacc[mt][nt] = __builtin_amdgcn_mfma_f32_16x16x32_bf16(
                        kf[mt], qf[nt][ks], sacc[mt][nt], 0, 0, 0);
            __builtin_amdgcn_s_setprio(0);
        }

        if (dlt == 4 || dlt == -4) {
#pragma unroll
            for (int mt = 0; mt < 4; ++mt)
#pragma unroll
                for (int nt = 0; nt < 4; ++nt)
#pragma unroll
                    for (int r = 0; r < 4; ++r) {
                        int kl = mt * 16 + quad * 4 + r;
                        int ql = nt * 16 + c16;
                        bool ok = (dlt < 0) ? (kl >= ql) : (kl <= ql);
                        if (!ok) sacc[mt][nt][r] = -1e30f;
                    }
        }

        float pm[4];
#pragma unroll
        for (int nt = 0; nt < 4; ++nt) {
            float a0 = fmaxf(fmaxf(sacc[0][nt][0], sacc[0][nt][1]),
                             fmaxf(sacc[0][nt][2], sacc[0][nt][3]));
            float a1 = fmaxf(fmaxf(sacc[1][nt][0], sacc[1][nt][1]),
                             fmaxf(sacc[1][nt][2], sacc[1][nt][3]));
            float a2 = fmaxf(fmaxf(sacc[2][nt][0], sacc[2][nt][1]),
                             fmaxf(sacc[2][nt][2], sacc[2][nt][3]));
            float a3 = fmaxf(fmaxf(sacc[3][nt][0], sacc[3][nt][1]),
                             fmaxf(sacc[3][nt][2], sacc[3][nt][3]));
            pm[nt] = fmaxf(fmaxf(a0, a1), fmaxf(a2, a3));
            pm[nt] = fmaxf(pm[nt], __shfl_xor(pm[nt], 16, 64));
            pm[nt] = fmaxf(pm[nt], __shfl_xor(pm[nt], 32, 64));
        }
        float al[4];
#pragma unroll
        for (int nt = 0; nt < 4; ++nt) {
            float mn = fmaxf(mrow[nt], pm[nt]);
            al[nt] = exp2f((mrow[nt] - mn) * CC);
            mrow[nt] = mn;
        }
        float ps[4] = {0.f, 0.f, 0.f, 0.f};
#pragma unroll
        for (int mt = 0; mt < 4; ++mt)
#pragma unroll
            for (int nt = 0; nt < 4; ++nt)
#pragma unroll
                for (int r = 0; r < 4; ++r) {
                    float p = exp2f((sacc[mt][nt][r] - mrow[nt]) * CC);
                    sacc[mt][nt][r] = p;
                    ps[nt] += p;
                }
#pragma unroll
        for (int nt = 0; nt < 4; ++nt) {
            ps[nt] += __shfl_xor(ps[nt], 16, 64);
            ps[nt] += __shfl_xor(ps[nt], 32, 64);
            lsum[nt] = lsum[nt] * al[nt] + ps[nt];
        }

#pragma unroll
        for (int mt = 0; mt < 4; ++mt)
#pragma unroll
            for (int nt = 0; nt < 4; ++nt) {
                int row = nt * 16 + c16;
                int g   = (2 * mt + (quad >> 1)) ^ (row & 3);
                union { ushort u[4]; uint2 d; } t;
#pragma unroll
                for (int r = 0; r < 4; ++r) t.u[r] = f2bf(sacc[mt][nt][r]);
                *(uint2*)&sP[row * 72 + g * 8 + (quad & 1) * 4] = t.d;
            }

#pragma unroll
        for (int dt = 0; dt < 4; ++dt)
#pragma unroll
            for (int nq = 0; nq < 4; ++nq)
#pragma unroll
                for (int r = 0; r < 4; ++r)
                    oacc[dt][nq][r] *= al[nq];

#pragma unroll
        for (int ks = 0; ks < 2; ++ks) {
            bfrag8 vf[4], pf[4];
#pragma unroll
            for (int dt = 0; dt < 4; ++dt)
                vf[dt] = *(const bfrag8*)(vT + vT_b +
                    (size_t)(dt * 16 + c16) * SS + st * 64 + ks * 32 + quad * 8);
#pragma unroll
            for (int nq = 0; nq < 4; ++nq) {
                int row = nq * 16 + c16;
                int g   = (4 * ks + quad) ^ (row & 3);
                pf[nq] = *(const bfrag8*)&sP[row * 72 + g * 8];
            }
            __builtin_amdgcn_s_setprio(1);
#pragma unroll
            for (int dt = 0; dt < 4; ++dt)
#pragma unroll
                for (int nq = 0; nq < 4; ++nq)
                    oacc[dt][nq] = __builtin_amdgcn_mfma_f32_16x16x32_bf16(
                        vf[dt], pf[nq], oacc[dt][nq], 0, 0, 0);
            __builtin_amdgcn_s_setprio(0);
        }
    }

#pragma unroll
    for (int nq = 0; nq < 4; ++nq) {
        float inv = 1.f / lsum[nq];
        size_t rbase = ((size_t)b * SS + qt * 64 + nq * 16 + c16) * DD + h * HDIM;
#pragma unroll
        for (int dt = 0; dt < 4; ++dt) {
            union { ushort u[4]; uint2 d; } t;
#pragma unroll
            for (int r = 0; r < 4; ++r) t.u[r] = f2bf(oacc[dt][nq][r] * inv);
            *(uint2*)(out + rbase + dt * 16 + quad * 4) = t.d;
        }
    }
}

// ---------------------------------------------------------------------------
// out = LayerNorm(a + res) * g + b    (one block per row of D=1024)
// Fully vectorized loads/stores (G13): bf16 as uint2, f32 as float4.
// ---------------------------------------------------------------------------
__device__ __forceinline__ void ldv4(const float* p, float* o) {
    float4 v = *(const float4*)p;
    o[0] = v.x; o[1] = v.y; o[2] = v.z; o[3] = v.w;
}
__device__ __forceinline__ void ldv4(const ushort* p, float* o) {
    union { ushort u[4]; uint2 d; } t;
    t.d = *(const uint2*)p;
#pragma unroll
    for (int e = 0; e < 4; ++e) o[e] = bf2f(t.u[e]);
}
__device__ __forceinline__ void stv4(float* p, const float* v) {
    float4 t; t.x = v[0]; t.y = v[1]; t.z = v[2]; t.w = v[3];
    *(float4*)p = t;
}
__device__ __forceinline__ void stv4(ushort* p, const float* v) {
    union { ushort u[4]; uint2 d; } t;
#pragma unroll
    for (int e = 0; e < 4; ++e) t.u[e] = f2bf(v[e]);
    *(uint2*)p = t.d;
}

template <typename RT, typename OT>
__global__ __launch_bounds__(256) void add_ln(
    const ushort* __restrict__ a, const RT* __restrict__ res,
    const float* __restrict__ g, const float* __restrict__ bb,
    OT* __restrict__ out)
{
    const int row = blockIdx.x;
    const int tid = threadIdx.x;
    const size_t base = (size_t)row * DD + tid * 4;

    float av[4], rv[4], x[4];
    ldv4(a + base, av);
    ldv4(res + base, rv);
    float s1 = 0.f, s2 = 0.f;
#pragma unroll
    for (int e = 0; e < 4; ++e) {
        x[e] = av[e] + rv[e];
        s1 += x[e];
        s2 += x[e] * x[e];
    }
#pragma unroll
    for (int off = 32; off > 0; off >>= 1) {
        s1 += __shfl_down(s1, off, 64);
        s2 += __shfl_down(s2, off, 64);
    }
    __shared__ float r1[4], r2[4];
    const int wave = tid >> 6, lane = tid & 63;
    if (lane == 0) { r1[wave] = s1; r2[wave] = s2; }
    __syncthreads();
    float t1 = r1[0] + r1[1] + r1[2] + r1[3];
    float t2 = r2[0] + r2[1] + r2[2] + r2[3];
    float mu  = t1 * (1.f / DD);
    float var = t2 * (1.f / DD) - mu * mu;
    float rs  = rsqrtf(var + 1e-5f);

    float gv[4], bv[4], y[4];
    ldv4(g + (size_t)tid * 4, gv);
    ldv4(bb + (size_t)tid * 4, bv);
#pragma unroll
    for (int e = 0; e < 4; ++e)
        y[e] = (x[e] - mu) * rs * gv[e] + bv[e];
    stv4(out + base, y);
}

// ---------------------------------------------------------------------------
extern "C" void kernel_launch(void* const* d_in, const int* in_sizes, int n_in,
                              void* d_out, int out_size, void* d_ws, size_t ws_size,
                              hipStream_t stream)
{
    (void)in_sizes; (void)n_in; (void)out_size; (void)ws_size;

    const float* x  = (const float*)d_in[0];
    const float* Wq = (const float*)d_in[1];
    const float* bq = (const float*)d_in[2];
    const float* Wk = (const float*)d_in[3];
    const float* bk = (const float*)d_in[4];
    const float* Wv = (const float*)d_in[5];
    const float* bv = (const float*)d_in[6];
    const float* Wo = (const float*)d_in[7];
    const float* bo = (const float*)d_in[8];
    const float* g1 = (const float*)d_in[9];
    const float* b1 = (const float*)d_in[10];
    const float* W1 = (const float*)d_in[11];
    const float* c1 = (const float*)d_in[12];
    const float* W2 = (const float*)d_in[13];
    const float* c2 = (const float*)d_in[14];
    const float* g2 = (const float*)d_in[15];
    const float* b2 = (const float*)d_in[16];
    float* outp = (float*)d_out;

    char* ws = (char*)d_ws;
    const size_t MB = 1024 * 1024;
    ushort* WqkvT = (ushort*)(ws);            // [  0,  6): Wq^T|Wk^T|Wv^T
    ushort* WoT = (ushort*)(ws + 6  * MB);    // [  6,  8)
    ushort* W1t = (ushort*)(ws + 8  * MB);    // [  8, 16)
    ushort* W2t = (ushort*)(ws + 16 * MB);    // [ 16, 24)
    ushort* xb  = (ushort*)(ws + 24 * MB);    // [ 24, 40)
    ushort* qb  = (ushort*)(ws + 40 * MB);    // [ 40, 56)  qh [b][h][s][64]
    ushort* kb  = (ushort*)(ws + 56 * MB);    // [ 56, 72)  kh [b][h][s][64]
    ushort* vT  = (ushort*)(ws + 72 * MB);    // [ 72, 88)  [b][h][dh][s]
    ushort* att = (ushort*)(ws + 88 * MB);    // [ 88,104)
    ushort* aproj = qb;                       // qh dead after attn
    ushort* hbuf  = att;
    ushort* m1  = (ushort*)(ws + 24 * MB);    // [ 24, 88)
    ushort* fbuf = (ushort*)(ws + 104 * MB);  // [104,120)

    dim3 blk(256, 1, 1);
    dim3 gD1((DD / 128) * (MROWS / 128), 1, 1);     // 512 blocks, 1D
    dim3 gQKV1((3 * DD / 128) * (MROWS / 128), 1, 1); // 1536 blocks
    dim3 gF1((FF / 128) * (MROWS / 128), 1, 1);     // 2048 blocks
    dim3 ga(SS / 64, HH, BB);
    dim3 gl(MROWS, 1, 1);

    hipLaunchKernelGGL(cvt_transpose_all, dim3(128, 32, 6), blk, 0, stream,
                       Wq, Wk, Wv, Wo, W1, W2, WqkvT, WoT, W1t, W2t);
    hipLaunchKernelGGL(cvt_f32_bf16, dim3(8192), blk, 0, stream, x, xb);

    hipLaunchKernelGGL(gemm_qkv, gQKV1, blk, 0, stream, xb, WqkvT, bq, bk, bv, qb, kb, vT);

    hipLaunchKernelGGL(attn_flash, ga, dim3(64, 1, 1), 0, stream, qb, kb, vT, att);

    hipLaunchKernelGGL(gemm_bt, gD1, blk, 0, stream, att, WoT, bo, aproj, MROWS, DD, DD, 0);
    hipLaunchKernelGGL((add_ln<float, ushort>), gl, blk, 0, stream, aproj, x, g1, b1, hbuf);

    hipLaunchKernelGGL(gemm_bt, gF1, blk, 0, stream, hbuf, W1t, c1, m1, MROWS, FF, DD, 1);
    hipLaunchKernelGGL(gemm_bt, gD1, blk, 0, stream, m1, W2t, c2, fbuf, MROWS, DD, FF, 0);
    hipLaunchKernelGGL((add_ln<ushort, float>), gl, blk, 0, stream, fbuf, hbuf, g2, b2, outp);
}

// Round 10
// 472.662 us; speedup vs baseline: 1.1427x; 1.0383x over previous
//
#include <hip/hip_runtime.h>
#include <hip/hip_bf16.h>

#define BB 2
#define SS 4096
#define DD 1024
#define HH 16
#define WW 256
#define FF 4096
#define HDIM 64
#define NBLK (SS / WW)       /* 16 */
#define MROWS (BB * SS)      /* 8192 */

typedef short bfrag8 __attribute__((ext_vector_type(8)));
typedef float floatx4 __attribute__((ext_vector_type(4)));

__device__ __forceinline__ float bf2f(ushort u) {
    union { uint i; float f; } c; c.i = ((uint)u) << 16; return c.f;
}
__device__ __forceinline__ ushort f2bf(float f) {
    union { float f; uint i; } c; c.f = f;
    uint r = (c.i + 0x7FFFu + ((c.i >> 16) & 1u)) >> 16;
    return (ushort)r;
}
// gelu(tanh approx) == x * sigmoid(2z), z = 0.79788456(x + 0.044715 x^3)
__device__ __forceinline__ float gelu_fast(float x) {
    float z2 = 1.5957691216057308f * x * (1.f + 0.044715f * x * x); // 2z
    return x / (1.f + __expf(-z2));
}

// async global->LDS, 16B per lane. LDS dest must be contiguous in lane order.
__device__ __forceinline__ void gload_lds16(const ushort* g, ushort* l) {
    __builtin_amdgcn_global_load_lds(
        (const __attribute__((address_space(1))) void*)g,
        (__attribute__((address_space(3))) void*)l, 16, 0, 0);
}

// ---------------------------------------------------------------------------
// f32 -> bf16 bulk convert (grid * 1024 elements)
// ---------------------------------------------------------------------------
__global__ __launch_bounds__(256) void cvt_f32_bf16(
    const float* __restrict__ in, ushort* __restrict__ out)
{
    size_t i = ((size_t)blockIdx.x * 256 + threadIdx.x) * 4;
    float4 v = *(const float4*)(in + i);
    union { ushort u[4]; uint2 d; } t;
    t.u[0] = f2bf(v.x); t.u[1] = f2bf(v.y);
    t.u[2] = f2bf(v.z); t.u[3] = f2bf(v.w);
    *(uint2*)(out + i) = t.d;
}

// ---------------------------------------------------------------------------
// Fused transpose-convert of ALL weights: f32 [K][N] -> bf16 [N][K].
// grid = (128, 32, 6); z selects the weight. 32x32 LDS tiles.
// ---------------------------------------------------------------------------
__global__ __launch_bounds__(256) void cvt_transpose_all(
    const float* __restrict__ Wq, const float* __restrict__ Wk,
    const float* __restrict__ Wv, const float* __restrict__ Wo,
    const float* __restrict__ W1, const float* __restrict__ W2,
    ushort* __restrict__ WqkvT, ushort* __restrict__ WoT,
    ushort* __restrict__ W1t, ushort* __restrict__ W2t)
{
    __shared__ ushort sT[32][33];
    const int z = blockIdx.z;
    const float* in; ushort* out; int K, N, n0, k0;
    if (z < 4) {
        if (blockIdx.x >= 32) return;
        in  = (z == 0) ? Wq : (z == 1) ? Wk : (z == 2) ? Wv : Wo;
        out = (z < 3) ? WqkvT + (size_t)z * 1024 * 1024 : WoT;
        K = 1024; N = 1024;
        n0 = blockIdx.x * 32; k0 = blockIdx.y * 32;
    } else if (z == 4) {
        in = W1; out = W1t; K = 1024; N = 4096;
        n0 = blockIdx.x * 32; k0 = blockIdx.y * 32;
    } else {
        in = W2; out = W2t; K = 4096; N = 1024;
        n0 = blockIdx.y * 32; k0 = blockIdx.x * 32;
    }

    const int r  = threadIdx.x >> 3;        // 0..31
    const int c4 = (threadIdx.x & 7) * 4;   // 0..28

    float4 v = *(const float4*)(in + (size_t)(k0 + r) * N + n0 + c4);
    sT[c4 + 0][r] = f2bf(v.x);
    sT[c4 + 1][r] = f2bf(v.y);
    sT[c4 + 2][r] = f2bf(v.z);
    sT[c4 + 3][r] = f2bf(v.w);
    __syncthreads();
    union { ushort u[4]; uint2 d; } t;
#pragma unroll
    for (int e = 0; e < 4; ++e) t.u[e] = sT[r][c4 + e];
    *(uint2*)(out + (size_t)(n0 + r) * K + k0 + c4) = t.d;
}

// ---------------------------------------------------------------------------
// GEMM: C[M,N] = A[M,K] @ B[K,N] + bias[N], Bt = B^T [N][K] bf16.
// Verified 2-phase 128x128 tile, BK=64, global_load_lds width-16 staging,
// XOR-swizzled k-granules, XCD-aware 1D grid.
// ---------------------------------------------------------------------------
__global__ __launch_bounds__(256) void gemm_bt(
    const ushort* __restrict__ A, const ushort* __restrict__ Bt,
    const float* __restrict__ bias, ushort* __restrict__ C,
    int M, int N, int K, int act)
{
    __shared__ ushort sA[128 * 64];
    __shared__ ushort sB[128 * 64];

    const int tid  = threadIdx.x;
    const int nx   = N >> 7;
    const int nyg  = (M >> 7) >> 3;          // y-panels per XCD
    const int gid  = blockIdx.x;
    const int j    = gid >> 3;
    const int m0   = ((gid & 7) * nyg + j / nx) * 128;
    const int n0   = (j % nx) * 128;
    const int wave = tid >> 6;
    const int lane = tid & 63;
    const int wm   = (wave >> 1) * 64;
    const int wn   = (wave & 1) * 64;
    const int lrow = lane & 15;
    const int quad = lane >> 4;

    floatx4 acc[4][4];
#pragma unroll
    for (int i = 0; i < 4; ++i)
#pragma unroll
        for (int j2 = 0; j2 < 4; ++j2)
            acc[i][j2] = (floatx4){0.f, 0.f, 0.f, 0.f};

    for (int k0 = 0; k0 < K; k0 += 64) {
#pragma unroll
        for (int it = 0; it < 4; ++it) {
            int c    = it * 256 + tid;            // 0..1023 chunks of 16B
            int row  = c >> 3;
            int scol = ((c ^ (row & 7)) & 7) << 3;  // XOR-swizzled source col
            gload_lds16(A  + (size_t)(m0 + row) * K + k0 + scol, &sA[c * 8]);
            gload_lds16(Bt + (size_t)(n0 + row) * K + k0 + scol, &sB[c * 8]);
        }
        __syncthreads();

#pragma unroll
        for (int ks = 0; ks < 2; ++ks) {
            bfrag8 af[4], bfv[4];
#pragma unroll
            for (int mt = 0; mt < 4; ++mt) {
                int row = wm + mt * 16 + lrow;
                int G   = ks * 4 + quad;
                af[mt] = *(const bfrag8*)&sA[row * 64 + (((G ^ row) & 7) << 3) + ((G >> 3) << 6)];
            }
#pragma unroll
            for (int nt = 0; nt < 4; ++nt) {
                int row = wn + nt * 16 + lrow;
                int G   = ks * 4 + quad;
                bfv[nt] = *(const bfrag8*)&sB[row * 64 + (((G ^ row) & 7) << 3) + ((G >> 3) << 6)];
            }
#pragma unroll
            for (int mt = 0; mt < 4; ++mt)
#pragma unroll
                for (int nt = 0; nt < 4; ++nt)
                    acc[mt][nt] = __builtin_amdgcn_mfma_f32_16x16x32_bf16(
                        bfv[nt], af[mt], acc[mt][nt], 0, 0, 0);
        }
        __syncthreads();
    }

    // epilogue: m = m0+wm+mt*16+lrow (lane), n-chunk = n0+wn+nt*16+quad*4 (regs)
#pragma unroll
    for (int nt = 0; nt < 4; ++nt) {
        int nb = n0 + wn + nt * 16 + quad * 4;
        union { float4 v; float f[4]; } b4;
        b4.v = *(const float4*)(bias + nb);
#pragma unroll
        for (int mt = 0; mt < 4; ++mt) {
            int row = m0 + wm + mt * 16 + lrow;
            union { ushort u[4]; uint2 d; } t;
#pragma unroll
            for (int r = 0; r < 4; ++r) {
                float v = acc[mt][nt][r] + b4.f[r];
                if (act) v = gelu_fast(v);
                t.u[r] = f2bf(v);
            }
            *(uint2*)(C + (size_t)row * N + nb) = t.d;
        }
    }
}

// ---------------------------------------------------------------------------
// Fused QKV GEMM (verified 2-phase 128x128): A[8192][1024] @ [Wq|Wk|Wv]
// (Bt = [3072][1024]), BK=64, swizzled staging, XCD-aware 1D grid
// (1536 blocks). cols [0,1024) -> qh [b][h][s][64]; [1024,2048) -> kh
// [b][h][s][64] (head-grouped for attn locality); [2048,3072) ->
// vT [b][h][dh][s] (swapped-operand MFMA).
// ---------------------------------------------------------------------------
__global__ __launch_bounds__(256) void gemm_qkv(
    const ushort* __restrict__ A, const ushort* __restrict__ Bt,
    const float* __restrict__ bq, const float* __restrict__ bk,
    const float* __restrict__ bv,
    ushort* __restrict__ qh, ushort* __restrict__ kh, ushort* __restrict__ vT)
{
    __shared__ ushort sA[128 * 64];
    __shared__ ushort sB[128 * 64];
    const int K = DD;

    const int tid  = threadIdx.x;
    const int nx   = 24, nyg = 8;
    const int gid  = blockIdx.x;
    const int j    = gid >> 3;
    const int m0   = ((gid & 7) * nyg + j / nx) * 128;
    const int n0   = (j % nx) * 128;
    const int wave = tid >> 6;
    const int lane = tid & 63;
    const int wm   = (wave >> 1) * 64;
    const int wn   = (wave & 1) * 64;
    const int lrow = lane & 15;
    const int quad = lane >> 4;
    const int sel  = n0 >> 10;               // block-uniform: 0=q 1=k 2=v

    floatx4 acc[4][4];
#pragma unroll
    for (int i = 0; i < 4; ++i)
#pragma unroll
        for (int j2 = 0; j2 < 4; ++j2)
            acc[i][j2] = (floatx4){0.f, 0.f, 0.f, 0.f};

    for (int k0 = 0; k0 < K; k0 += 64) {
#pragma unroll
        for (int it = 0; it < 4; ++it) {
            int c    = it * 256 + tid;
            int row  = c >> 3;
            int scol = ((c ^ (row & 7)) & 7) << 3;
            gload_lds16(A  + (size_t)(m0 + row) * K + k0 + scol, &sA[c * 8]);
            gload_lds16(Bt + (size_t)(n0 + row) * K + k0 + scol, &sB[c * 8]);
        }
        __syncthreads();

#pragma unroll
        for (int ks = 0; ks < 2; ++ks) {
            bfrag8 af[4], bfv[4];
#pragma unroll
            for (int mt = 0; mt < 4; ++mt) {
                int row = wm + mt * 16 + lrow;
                int G   = ks * 4 + quad;
                af[mt] = *(const bfrag8*)&sA[row * 64 + (((G ^ row) & 7) << 3)];
            }
#pragma unroll
            for (int nt = 0; nt < 4; ++nt) {
                int row = wn + nt * 16 + lrow;
                int G   = ks * 4 + quad;
                bfv[nt] = *(const bfrag8*)&sB[row * 64 + (((G ^ row) & 7) << 3)];
            }
            if (sel < 2) {
#pragma unroll
                for (int mt = 0; mt < 4; ++mt)
#pragma unroll
                    for (int nt = 0; nt < 4; ++nt)
                        acc[mt][nt] = __builtin_amdgcn_mfma_f32_16x16x32_bf16(
                            bfv[nt], af[mt], acc[mt][nt], 0, 0, 0);
            } else {
#pragma unroll
                for (int mt = 0; mt < 4; ++mt)
#pragma unroll
                    for (int nt = 0; nt < 4; ++nt)
                        acc[mt][nt] = __builtin_amdgcn_mfma_f32_16x16x32_bf16(
                            af[mt], bfv[nt], acc[mt][nt], 0, 0, 0);
            }
        }
        __syncthreads();
    }

    if (sel < 2) {
        ushort* C = (sel == 0) ? qh : kh;
        const float* bias = (sel == 0) ? bq : bk;
        const int colbase = n0 + wn;
#pragma unroll
        for (int nt = 0; nt < 4; ++nt) {
            int nb = (colbase + nt * 16 + quad * 4) & 1023;  // d in [0,1024)
            int h  = nb >> 6, dh = nb & 63;                  // dh <= 60
            union { float4 v; float f[4]; } b4;
            b4.v = *(const float4*)(bias + nb);
#pragma unroll
            for (int mt = 0; mt < 4; ++mt) {
                int row = m0 + wm + mt * 16 + lrow;
                int b = row >> 12, s = row & 4095;
                union { ushort u[4]; uint2 d; } t;
#pragma unroll
                for (int r = 0; r < 4; ++r) t.u[r] = f2bf(acc[mt][nt][r] + b4.f[r]);
                *(uint2*)(C + ((size_t)(b * HH + h) * SS + s) * HDIM + dh) = t.d;
            }
        }
    } else {
        const int colbase = n0 + wn;
#pragma unroll
        for (int nt = 0; nt < 4; ++nt) {
            int cc = (colbase + nt * 16 + lrow) & 1023;
            int h = cc >> 6, dh = cc & 63;
            float bb = bv[cc];
#pragma unroll
            for (int mt = 0; mt < 4; ++mt) {
                int row0 = m0 + wm + mt * 16 + (quad << 2);
                int b = row0 >> 12, s = row0 & 4095;
                union { ushort u[4]; uint2 d; } t;
#pragma unroll
                for (int r = 0; r < 4; ++r) t.u[r] = f2bf(acc[mt][nt][r] + bb);
                *(uint2*)(vT + (size_t)(((b * HH + h) * HDIM + dh)) * SS + s) = t.d;
            }
        }
    }
}

// ---------------------------------------------------------------------------
// Barrier-free MFMA flash attention. One wave per block; block = (qt, h, b).
// Q,K head-grouped [b][h][s][64]; V^T [b][h][dh][s]. Per K-tile:
// vf loads issued FIRST (T14 issue-early: latency hides under QK+softmax),
// QK MFMA (setprio), online softmax with T13 defer-max (skip O-rescale when
// __all(pm - mrow <= 32) -- P bounded by 2^5.8, safe in bf16), P via
// swizzled LDS, PV MFMA (setprio). No __syncthreads.
// ---------------------------------------------------------------------------
__global__ __launch_bounds__(64, 2) void attn_flash(
    const ushort* __restrict__ q, const ushort* __restrict__ k,
    const ushort* __restrict__ vT, ushort* __restrict__ out)
{
    __shared__ ushort sP[64 * 72];

    const int qt = blockIdx.x, h = blockIdx.y, b = blockIdx.z;
    const int lane = threadIdx.x;
    const int c16  = lane & 15;
    const int quad = lane >> 4;
    const float CC = 0.18033688011112042f;   // (1/sqrt(64)) * log2(e)

    bfrag8 qf[4][2];
    {
        const size_t qbase = ((size_t)(b * HH + h) * SS + qt * 64) * HDIM;
#pragma unroll
        for (int nt = 0; nt < 4; ++nt)
#pragma unroll
            for (int ks = 0; ks < 2; ++ks)
                qf[nt][ks] = *(const bfrag8*)(q + qbase +
                    (size_t)(nt * 16 + c16) * HDIM + ks * 32 + quad * 8);
    }

    floatx4 oacc[4][4];
#pragma unroll
    for (int i = 0; i < 4; ++i)
#pragma unroll
        for (int j = 0; j < 4; ++j)
            oacc[i][j] = (floatx4){0.f, 0.f, 0.f, 0.f};
    float mrow[4], lsum[4];
#pragma unroll
    for (int i = 0; i < 4; ++i) { mrow[i] = -1e30f; lsum[i] = 0.f; }

    const int st0 = (qt - 4 > 0) ? qt - 4 : 0;
    const int st1 = (qt + 4 < 63) ? qt + 4 : 63;
    const size_t kb_b  = (size_t)(b * HH + h) * SS * HDIM;
    const size_t vT_b  = (size_t)((b * HH + h) * HDIM) * SS;

    for (int st = st0; st <= st1; ++st) {
        const int dlt = st - qt;

        // T14: V^T fragment loads issued before QK -- independent of the
        // softmax chain; their latency hides under QK MFMA + softmax VALU.
        bfrag8 vf[2][4];
#pragma unroll
        for (int ks = 0; ks < 2; ++ks)
#pragma unroll
            for (int dt = 0; dt < 4; ++dt)
                vf[ks][dt] = *(const bfrag8*)(vT + vT_b +
                    (size_t)(dt * 16 + c16) * SS + st * 64 + ks * 32 + quad * 8);

        floatx4 sacc[4][4];
#pragma unroll
        for (int i = 0; i < 4; ++i)
#pragma unroll
            for (int j = 0; j < 4; ++j)
                sacc[i][j] = (floatx4){0.f, 0.f, 0.f, 0.f};
#pragma unroll
        for (int ks = 0; ks < 2; ++ks) {
            bfrag8 kf[4];
#pragma unroll
            for (int mt = 0; mt < 4; ++mt)
                kf[mt] = *(const bfrag8*)(k + kb_b +
                    (size_t)(st * 64 + mt * 16 + c16) * HDIM + ks * 32 + quad * 8);
            __builtin_amdgcn_s_setprio(1);
#pragma unroll
            for (int mt = 0; mt < 4; ++mt)
#pragma unroll
                for (int nt = 0; nt < 4; ++nt)
                    sacc[mt][nt] = __builtin_amdgcn_mfma_f32_16x16x32_bf16(
                        kf[mt], qf[nt][ks], sacc[mt][nt], 0, 0, 0);
            __builtin_amdgcn_s_setprio(0);
        }

        if (dlt == 4 || dlt == -4) {
#pragma unroll
            for (int mt = 0; mt < 4; ++mt)
#pragma unroll
                for (int nt = 0; nt < 4; ++nt)
#pragma unroll
                    for (int r = 0; r < 4; ++r) {
                        int kl = mt * 16 + quad * 4 + r;
                        int ql = nt * 16 + c16;
                        bool ok = (dlt < 0) ? (kl >= ql) : (kl <= ql);
                        if (!ok) sacc[mt][nt][r] = -1e30f;
                    }
        }

        float pm[4];
#pragma unroll
        for (int nt = 0; nt < 4; ++nt) {
            float a0 = fmaxf(fmaxf(sacc[0][nt][0], sacc[0][nt][1]),
                             fmaxf(sacc[0][nt][2], sacc[0][nt][3]));
            float a1 = fmaxf(fmaxf(sacc[1][nt][0], sacc[1][nt][1]),
                             fmaxf(sacc[1][nt][2], sacc[1][nt][3]));
            float a2 = fmaxf(fmaxf(sacc[2][nt][0], sacc[2][nt][1]),
                             fmaxf(sacc[2][nt][2], sacc[2][nt][3]));
            float a3 = fmaxf(fmaxf(sacc[3][nt][0], sacc[3][nt][1]),
                             fmaxf(sacc[3][nt][2], sacc[3][nt][3]));
            pm[nt] = fmaxf(fmaxf(a0, a1), fmaxf(a2, a3));
            pm[nt] = fmaxf(pm[nt], __shfl_xor(pm[nt], 16, 64));
            pm[nt] = fmaxf(pm[nt], __shfl_xor(pm[nt], 32, 64));
        }

        // T13 defer-max: wave-uniform skip of the O/l rescale when the new
        // tile max exceeds the running max by <= 32 raw-score units
        // (exp2(32*CC) = 2^5.77 ~ 55 -- bounded, bf16-safe).
        const int defer = __all((pm[0] - mrow[0] <= 32.f) &
                                (pm[1] - mrow[1] <= 32.f) &
                                (pm[2] - mrow[2] <= 32.f) &
                                (pm[3] - mrow[3] <= 32.f));
        float al[4];
        if (!defer) {
#pragma unroll
            for (int nt = 0; nt < 4; ++nt) {
                float mn = fmaxf(mrow[nt], pm[nt]);
                al[nt] = exp2f((mrow[nt] - mn) * CC);
                mrow[nt] = mn;
            }
        } else {
#pragma unroll
            for (int nt = 0; nt < 4; ++nt) al[nt] = 1.f;
        }

        float ps[4] = {0.f, 0.f, 0.f, 0.f};
#pragma unroll
        for (int mt = 0; mt < 4; ++mt)
#pragma unroll
            for (int nt = 0; nt < 4; ++nt)
#pragma unroll
                for (int r = 0; r < 4; ++r) {
                    float p = exp2f((sacc[mt][nt][r] - mrow[nt]) * CC);
                    sacc[mt][nt][r] = p;
                    ps[nt] += p;
                }
#pragma unroll
        for (int nt = 0; nt < 4; ++nt) {
            ps[nt] += __shfl_xor(ps[nt], 16, 64);
            ps[nt] += __shfl_xor(ps[nt], 32, 64);
            lsum[nt] = lsum[nt] * al[nt] + ps[nt];
        }

#pragma unroll
        for (int mt = 0; mt < 4; ++mt)
#pragma unroll
            for (int nt = 0; nt < 4; ++nt) {
                int row = nt * 16 + c16;
                int g   = (2 * mt + (quad >> 1)) ^ (row & 3);
                union { ushort u[4]; uint2 d; } t;
#pragma unroll
                for (int r = 0; r < 4; ++r) t.u[r] = f2bf(sacc[mt][nt][r]);
                *(uint2*)&sP[row * 72 + g * 8 + (quad & 1) * 4] = t.d;
            }

        if (!defer) {
#pragma unroll
            for (int dt = 0; dt < 4; ++dt)
#pragma unroll
                for (int nq = 0; nq < 4; ++nq)
#pragma unroll
                    for (int r = 0; r < 4; ++r)
                        oacc[dt][nq][r] *= al[nq];
        }

#pragma unroll
        for (int ks = 0; ks < 2; ++ks) {
            bfrag8 pf[4];
#pragma unroll
            for (int nq = 0; nq < 4; ++nq) {
                int row = nq * 16 + c16;
                int g   = (4 * ks + quad) ^ (row & 3);
                pf[nq] = *(const bfrag8*)&sP[row * 72 + g * 8];
            }
            __builtin_amdgcn_s_setprio(1);
#pragma unroll
            for (int dt = 0; dt < 4; ++dt)
#pragma unroll
                for (int nq = 0; nq < 4; ++nq)
                    oacc[dt][nq] = __builtin_amdgcn_mfma_f32_16x16x32_bf16(
                        vf[ks][dt], pf[nq], oacc[dt][nq], 0, 0, 0);
            __builtin_amdgcn_s_setprio(0);
        }
    }

#pragma unroll
    for (int nq = 0; nq < 4; ++nq) {
        float inv = 1.f / lsum[nq];
        size_t rbase = ((size_t)b * SS + qt * 64 + nq * 16 + c16) * DD + h * HDIM;
#pragma unroll
        for (int dt = 0; dt < 4; ++dt) {
            union { ushort u[4]; uint2 d; } t;
#pragma unroll
            for (int r = 0; r < 4; ++r) t.u[r] = f2bf(oacc[dt][nq][r] * inv);
            *(uint2*)(out + rbase + dt * 16 + quad * 4) = t.d;
        }
    }
}

// ---------------------------------------------------------------------------
// out = LayerNorm(a + res) * g + b    (one block per row of D=1024)
// Fully vectorized loads/stores (G13): bf16 as uint2, f32 as float4.
// ---------------------------------------------------------------------------
__device__ __forceinline__ void ldv4(const float* p, float* o) {
    float4 v = *(const float4*)p;
    o[0] = v.x; o[1] = v.y; o[2] = v.z; o[3] = v.w;
}
__device__ __forceinline__ void ldv4(const ushort* p, float* o) {
    union { ushort u[4]; uint2 d; } t;
    t.d = *(const uint2*)p;
#pragma unroll
    for (int e = 0; e < 4; ++e) o[e] = bf2f(t.u[e]);
}
__device__ __forceinline__ void stv4(float* p, const float* v) {
    float4 t; t.x = v[0]; t.y = v[1]; t.z = v[2]; t.w = v[3];
    *(float4*)p = t;
}
__device__ __forceinline__ void stv4(ushort* p, const float* v) {
    union { ushort u[4]; uint2 d; } t;
#pragma unroll
    for (int e = 0; e < 4; ++e) t.u[e] = f2bf(v[e]);
    *(uint2*)p = t.d;
}

template <typename RT, typename OT>
__global__ __launch_bounds__(256) void add_ln(
    const ushort* __restrict__ a, const RT* __restrict__ res,
    const float* __restrict__ g, const float* __restrict__ bb,
    OT* __restrict__ out)
{
    const int row = blockIdx.x;
    const int tid = threadIdx.x;
    const size_t base = (size_t)row * DD + tid * 4;

    float av[4], rv[4], x[4];
    ldv4(a + base, av);
    ldv4(res + base, rv);
    float s1 = 0.f, s2 = 0.f;
#pragma unroll
    for (int e = 0; e < 4; ++e) {
        x[e] = av[e] + rv[e];
        s1 += x[e];
        s2 += x[e] * x[e];
    }
#pragma unroll
    for (int off = 32; off > 0; off >>= 1) {
        s1 += __shfl_down(s1, off, 64);
        s2 += __shfl_down(s2, off, 64);
    }
    __shared__ float r1[4], r2[4];
    const int wave = tid >> 6, lane = tid & 63;
    if (lane == 0) { r1[wave] = s1; r2[wave] = s2; }
    __syncthreads();
    float t1 = r1[0] + r1[1] + r1[2] + r1[3];
    float t2 = r2[0] + r2[1] + r2[2] + r2[3];
    float mu  = t1 * (1.f / DD);
    float var = t2 * (1.f / DD) - mu * mu;
    float rs  = rsqrtf(var + 1e-5f);

    float gv[4], bv[4], y[4];
    ldv4(g + (size_t)tid * 4, gv);
    ldv4(bb + (size_t)tid * 4, bv);
#pragma unroll
    for (int e = 0; e < 4; ++e)
        y[e] = (x[e] - mu) * rs * gv[e] + bv[e];
    stv4(out + base, y);
}

// ---------------------------------------------------------------------------
extern "C" void kernel_launch(void* const* d_in, const int* in_sizes, int n_in,
                              void* d_out, int out_size, void* d_ws, size_t ws_size,
                              hipStream_t stream)
{
    (void)in_sizes; (void)n_in; (void)out_size; (void)ws_size;

    const float* x  = (const float*)d_in[0];
    const float* Wq = (const float*)d_in[1];
    const float* bq = (const float*)d_in[2];
    const float* Wk = (const float*)d_in[3];
    const float* bk = (const float*)d_in[4];
    const float* Wv = (const float*)d_in[5];
    const float* bv = (const float*)d_in[6];
    const float* Wo = (const float*)d_in[7];
    const float* bo = (const float*)d_in[8];
    const float* g1 = (const float*)d_in[9];
    const float* b1 = (const float*)d_in[10];
    const float* W1 = (const float*)d_in[11];
    const float* c1 = (const float*)d_in[12];
    const float* W2 = (const float*)d_in[13];
    const float* c2 = (const float*)d_in[14];
    const float* g2 = (const float*)d_in[15];
    const float* b2 = (const float*)d_in[16];
    float* outp = (float*)d_out;

    char* ws = (char*)d_ws;
    const size_t MB = 1024 * 1024;
    ushort* WqkvT = (ushort*)(ws);            // [  0,  6): Wq^T|Wk^T|Wv^T
    ushort* WoT = (ushort*)(ws + 6  * MB);    // [  6,  8)
    ushort* W1t = (ushort*)(ws + 8  * MB);    // [  8, 16)
    ushort* W2t = (ushort*)(ws + 16 * MB);    // [ 16, 24)
    ushort* xb  = (ushort*)(ws + 24 * MB);    // [ 24, 40)
    ushort* qb  = (ushort*)(ws + 40 * MB);    // [ 40, 56)  qh [b][h][s][64]
    ushort* kb  = (ushort*)(ws + 56 * MB);    // [ 56, 72)  kh [b][h][s][64]
    ushort* vT  = (ushort*)(ws + 72 * MB);    // [ 72, 88)  [b][h][dh][s]
    ushort* att = (ushort*)(ws + 88 * MB);    // [ 88,104)
    ushort* aproj = qb;                       // qh dead after attn
    ushort* hbuf  = att;
    ushort* m1  = (ushort*)(ws + 24 * MB);    // [ 24, 88)
    ushort* fbuf = (ushort*)(ws + 104 * MB);  // [104,120)

    dim3 blk(256, 1, 1);
    dim3 gD1((DD / 128) * (MROWS / 128), 1, 1);     // 512 blocks, 1D
    dim3 gQKV1((3 * DD / 128) * (MROWS / 128), 1, 1); // 1536 blocks
    dim3 gF1((FF / 128) * (MROWS / 128), 1, 1);     // 2048 blocks
    dim3 ga(SS / 64, HH, BB);
    dim3 gl(MROWS, 1, 1);

    hipLaunchKernelGGL(cvt_transpose_all, dim3(128, 32, 6), blk, 0, stream,
                       Wq, Wk, Wv, Wo, W1, W2, WqkvT, WoT, W1t, W2t);
    hipLaunchKernelGGL(cvt_f32_bf16, dim3(8192), blk, 0, stream, x, xb);

    hipLaunchKernelGGL(gemm_qkv, gQKV1, blk, 0, stream, xb, WqkvT, bq, bk, bv, qb, kb, vT);

    hipLaunchKernelGGL(attn_flash, ga, dim3(64, 1, 1), 0, stream, qb, kb, vT, att);

    hipLaunchKernelGGL(gemm_bt, gD1, blk, 0, stream, att, WoT, bo, aproj, MROWS, DD, DD, 0);
    hipLaunchKernelGGL((add_ln<float, ushort>), gl, blk, 0, stream, aproj, x, g1, b1, hbuf);

    hipLaunchKernelGGL(gemm_bt, gF1, blk, 0, stream, hbuf, W1t, c1, m1, MROWS, FF, DD, 1);
    hipLaunchKernelGGL(gemm_bt, gD1, blk, 0, stream, m1, W2t, c2, fbuf, MROWS, DD, FF, 0);
    hipLaunchKernelGGL((add_ln<ushort, float>), gl, blk, 0, stream, fbuf, hbuf, g2, b2, outp);
}